// Round 14
// baseline (4493.975 us; speedup 1.0000x reference)
//
#include <hip/hip_runtime.h>
#include <hip/hip_bf16.h>
#include <hip/hip_fp16.h>

// packed fp32 pair — __builtin_elementwise_fma ONLY (round-11: asm FMA 2x
// regression; round-12: float4 W loads neutral -> compiler already optimal).
typedef float v2f __attribute__((ext_vector_type(2)));
__device__ __forceinline__ v2f vfma2(v2f a, v2f b, v2f c) {
#if __has_builtin(__builtin_elementwise_fma)
    return __builtin_elementwise_fma(a, b, c);
#else
    v2f d; d.x = fmaf(a.x, b.x, c.x); d.y = fmaf(a.y, b.y, c.y); return d;
#endif
}

// MFMA vector types (ext vectors, NOT HIP structs)
typedef _Float16 half8v __attribute__((ext_vector_type(8)));
typedef float    f32x4  __attribute__((ext_vector_type(4)));

// ===========================================================================
// CSR build (multi-block scan; deterministic via per-row sort)
// ===========================================================================
__global__ void hist_kernel(const int* __restrict__ rows, int* __restrict__ counts, int E) {
    int i = blockIdx.x * blockDim.x + threadIdx.x;
    if (i < E) atomicAdd(&counts[rows[i]], 1);
}

__global__ void chunk_sum_kernel(const int* __restrict__ counts, int* __restrict__ chunk_sums, int V) {
    __shared__ int sh[256];
    int t = threadIdx.x;
    int i = blockIdx.x * 256 + t;
    sh[t] = (i < V) ? counts[i] : 0;
    __syncthreads();
    for (int st = 128; st > 0; st >>= 1) {
        if (t < st) sh[t] += sh[t + st];
        __syncthreads();
    }
    if (t == 0) chunk_sums[blockIdx.x] = sh[0];
}

__global__ void scan_chunks_kernel(int* __restrict__ cs, int n) {
    __shared__ int wsum[4];
    int t = threadIdx.x, lane = t & 63, w = t >> 6;
    int orig = (t < n) ? cs[t] : 0;
    int x = orig;
    #pragma unroll
    for (int d = 1; d < 64; d <<= 1) {
        int y = __shfl_up(x, d);
        if (lane >= d) x += y;
    }
    if (lane == 63) wsum[w] = x;
    __syncthreads();
    int wo = 0;
    for (int j = 0; j < w; ++j) wo += wsum[j];
    if (t < n) cs[t] = wo + x - orig;     // exclusive
}

__global__ void scan_final_kernel(const int* __restrict__ counts, const int* __restrict__ chunk_off,
                                  int* __restrict__ row_ptr, int V) {
    __shared__ int wsum[4];
    int t = threadIdx.x, lane = t & 63, w = t >> 6;
    int i = blockIdx.x * 256 + t;
    int x = (i < V) ? counts[i] : 0;
    #pragma unroll
    for (int d = 1; d < 64; d <<= 1) {
        int y = __shfl_up(x, d);
        if (lane >= d) x += y;
    }
    if (lane == 63) wsum[w] = x;
    __syncthreads();
    int wo = 0;
    for (int j = 0; j < w; ++j) wo += wsum[j];
    if (i < V) row_ptr[i + 1] = chunk_off[blockIdx.x] + wo + x;
    if (i == 0) row_ptr[0] = 0;
}

__global__ void init_cursor_kernel(const int* __restrict__ row_ptr, int* __restrict__ cursor, int V) {
    int i = blockIdx.x * blockDim.x + threadIdx.x;
    if (i < V) cursor[i] = row_ptr[i];
}

__global__ void scatter_kernel(const int* __restrict__ rows, const int* __restrict__ cols,
                               const float* __restrict__ vals, int* __restrict__ cursor,
                               int* __restrict__ cols_s, float* __restrict__ vals_s, int E) {
    int i = blockIdx.x * blockDim.x + threadIdx.x;
    if (i < E) {
        int r = rows[i];
        int p = atomicAdd(&cursor[r], 1);
        cols_s[p] = cols[i];
        vals_s[p] = vals[i];
    }
}

// canonical per-row order: insertion sort by (col, val-bits). Makes CSR
// bitwise-deterministic regardless of scatter's atomic ordering.
__global__ void sort_rows_kernel(const int* __restrict__ row_ptr, int* cols, float* vals, int V) {
    int v = blockIdx.x * blockDim.x + threadIdx.x;
    if (v >= V) return;
    int e0 = row_ptr[v], e1 = row_ptr[v + 1];
    for (int i = e0 + 1; i < e1; ++i) {
        int c = cols[i];
        unsigned xb = __float_as_uint(vals[i]);
        int j = i - 1;
        while (j >= e0) {
            int cj = cols[j];
            unsigned vj = __float_as_uint(vals[j]);
            if (cj > c || (cj == c && vj > xb)) {
                cols[j + 1] = cj; vals[j + 1] = __uint_as_float(vj);
                --j;
            } else break;
        }
        cols[j + 1] = c;
        vals[j + 1] = __uint_as_float(xb);
    }
}

// ===========================================================================
// transpose input (B,16,V) fp32 -> (V, B*16) fp16
// ===========================================================================
__global__ void transpose_in_kernel(const float* __restrict__ x, __half* __restrict__ X, int V) {
    int total = V * 128;
    for (int i = blockIdx.x * blockDim.x + threadIdx.x; i < total; i += gridDim.x * blockDim.x) {
        int v = i >> 7;
        int t = i & 127;          // t = b*16 + c
        X[i] = __float2half(x[t * V + v]);
    }
}

// ===========================================================================
// SpMM (parked: round-10 A/B showed batch-split neutral). One wave per node;
// 8-deep edge unroll.
// ===========================================================================
template <int VPT> struct PackT;
template <> struct PackT<1> { using T = float;  };
template <> struct PackT<2> { using T = float2; };
template <> struct PackT<4> { using T = float4; };

template <int VPT>
__global__ __launch_bounds__(256) void spmm2_kernel(
    const int* __restrict__ row_ptr, const int* __restrict__ cols,
    const float* __restrict__ vals, const __half2* __restrict__ src,
    __half2* dst, const __half2* prev, int V) {
    using T = typename PackT<VPT>::T;
    union U { T raw; __half2 h[VPT]; };
    int lane = threadIdx.x & 63;
    int v = (blockIdx.x << 2) | (threadIdx.x >> 6);
    if (v >= V) return;
    const int W = VPT * 64;
    const size_t row = (size_t)v * W + lane * VPT;

    float pr[2 * VPT];
    bool hasp = (prev != nullptr);
    if (hasp) {
        U pv; pv.raw = *(const T*)(prev + row);
        #pragma unroll
        for (int j = 0; j < VPT; ++j) {
            float2 f = __half22float2(pv.h[j]);
            pr[2 * j] = f.x; pr[2 * j + 1] = f.y;
        }
    }
    float acc[2 * VPT];
    #pragma unroll
    for (int j = 0; j < 2 * VPT; ++j) acc[j] = 0.f;

    int e0 = row_ptr[v], e1 = row_ptr[v + 1];
    int e = e0;
    for (; e + 8 <= e1; e += 8) {
        int   c[8]; float w[8]; U g[8];
        #pragma unroll
        for (int k = 0; k < 8; ++k) { c[k] = cols[e + k]; w[k] = vals[e + k]; }
        #pragma unroll
        for (int k = 0; k < 8; ++k)
            g[k].raw = *(const T*)(src + (size_t)c[k] * W + lane * VPT);
        #pragma unroll
        for (int k = 0; k < 8; ++k) {
            #pragma unroll
            for (int j = 0; j < VPT; ++j) {
                float2 f = __half22float2(g[k].h[j]);
                acc[2*j] += w[k] * f.x; acc[2*j+1] += w[k] * f.y;
            }
        }
    }
    for (; e + 4 <= e1; e += 4) {
        int   c[4]; float w[4]; U g[4];
        #pragma unroll
        for (int k = 0; k < 4; ++k) { c[k] = cols[e + k]; w[k] = vals[e + k]; }
        #pragma unroll
        for (int k = 0; k < 4; ++k)
            g[k].raw = *(const T*)(src + (size_t)c[k] * W + lane * VPT);
        #pragma unroll
        for (int k = 0; k < 4; ++k) {
            #pragma unroll
            for (int j = 0; j < VPT; ++j) {
                float2 f = __half22float2(g[k].h[j]);
                acc[2*j] += w[k] * f.x; acc[2*j+1] += w[k] * f.y;
            }
        }
    }
    for (; e < e1; ++e) {
        int c = cols[e]; float wv = vals[e];
        U g; g.raw = *(const T*)(src + (size_t)c * W + lane * VPT);
        #pragma unroll
        for (int j = 0; j < VPT; ++j) {
            float2 f = __half22float2(g.h[j]);
            acc[2*j] += wv * f.x; acc[2*j+1] += wv * f.y;
        }
    }
    if (hasp) {
        #pragma unroll
        for (int j = 0; j < 2 * VPT; ++j) acc[j] = 2.f * acc[j] - pr[j];
    }
    U o;
    #pragma unroll
    for (int j = 0; j < VPT; ++j) o.h[j] = __floats2half2_rn(acc[2*j], acc[2*j+1]);
    *(T*)(dst + row) = o.raw;
}

// ===========================================================================
// W prep for MFMA combine: W[kt][co] fp32 -> Bh/Bl[co][kt] fp16 two-term
// split. Transposed so B-fragments are contiguous 16B loads.
// ===========================================================================
__global__ void wprep_kernel(const float* __restrict__ W, __half* __restrict__ Bh,
                             __half* __restrict__ Bl, int KT) {
    int i = blockIdx.x * 256 + threadIdx.x;
    if (i >= KT * 64) return;
    int kt = i >> 6, co = i & 63;
    float w = W[(size_t)kt * 64 + co];
    __half h = __float2half_rn(w);
    Bh[(size_t)co * KT + kt] = h;
    Bl[(size_t)co * KT + kt] = __float2half_rn(w - __half2float(h));
}

// ===========================================================================
// combine64 via MFMA, v2 (round-14): round-13 counters showed MfmaUtil 5%,
// VALU 5%, occ 63%, VGPR 40 — load-latency serialization (compiler kept too
// few registers to pipeline the ~72 global loads). v2 PRELOADS all 8 A
// fragments (+ sc frag) into a statically-indexed register array BEFORE the
// MFMA loop: 9 independent 16B loads in flight at once, B loads hoistable.
// MFMA order unchanged (s asc, ct asc, bh then bl) -> bitwise identical to
// round-13 output. ~+36 VGPR (expect ~75 total).
// Aliasing: out may alias T1; each wave reads only its own 16-row range
// (all preloaded) before writing that range; ranges disjoint across waves.
// ===========================================================================
__global__ __launch_bounds__(256) void combine64_mfma_kernel(
    const __half* T0, const __half* T1, const __half* T2, const __half* T3,
    const __half* __restrict__ Bh, const __half* __restrict__ Bl,
    const float* __restrict__ bias,
    const __half* res, const __half* sc,
    const __half* __restrict__ Bsh, const __half* __restrict__ Bsl,
    __half* out, int relu, int V) {
    int l   = threadIdx.x & 63;
    int wid = threadIdx.x >> 6;
    int row0 = blockIdx.x * 64 + wid * 16;
    if (row0 >= V * 8) return;
    int lr = l & 15, lg = l >> 4;

    // ---- preload all A fragments (8 + optional sc) : maximizes MLP ----
    const __half* Ts[4] = {T0, T1, T2, T3};
    half8v a[8];
    #pragma unroll
    for (int s = 0; s < 8; ++s)
        a[s] = *(const half8v*)(Ts[s >> 1] + (size_t)(row0 + lr) * 64 + (s & 1) * 32 + lg * 8);
    half8v a2 = {};
    if (sc) a2 = *(const half8v*)(sc + (size_t)(row0 + lr) * 32 + lg * 8);

    f32x4 acc[4];
    #pragma unroll
    for (int ct = 0; ct < 4; ++ct) {
        float b = bias ? bias[ct * 16 + lr] : 0.f;
        acc[ct] = (f32x4){b, b, b, b};
    }

    #pragma unroll
    for (int s = 0; s < 8; ++s) {
        #pragma unroll
        for (int ct = 0; ct < 4; ++ct) {
            half8v bh = *(const half8v*)(Bh + (size_t)(ct * 16 + lr) * 256 + s * 32 + lg * 8);
            half8v bl = *(const half8v*)(Bl + (size_t)(ct * 16 + lr) * 256 + s * 32 + lg * 8);
            acc[ct] = __builtin_amdgcn_mfma_f32_16x16x32_f16(a[s], bh, acc[ct], 0, 0, 0);
            acc[ct] = __builtin_amdgcn_mfma_f32_16x16x32_f16(a[s], bl, acc[ct], 0, 0, 0);
        }
    }
    if (sc) {                                   // 32-ch shortcut, single K-slice
        #pragma unroll
        for (int ct = 0; ct < 4; ++ct) {
            half8v bh = *(const half8v*)(Bsh + (size_t)(ct * 16 + lr) * 32 + lg * 8);
            half8v bl = *(const half8v*)(Bsl + (size_t)(ct * 16 + lr) * 32 + lg * 8);
            acc[ct] = __builtin_amdgcn_mfma_f32_16x16x32_f16(a2, bh, acc[ct], 0, 0, 0);
            acc[ct] = __builtin_amdgcn_mfma_f32_16x16x32_f16(a2, bl, acc[ct], 0, 0, 0);
        }
    }

    #pragma unroll
    for (int ct = 0; ct < 4; ++ct) {
        #pragma unroll
        for (int j = 0; j < 4; ++j) {
            int r = row0 + lg * 4 + j;
            int c = ct * 16 + lr;
            float v = acc[ct][j];
            if (res) v += __half2float(res[(size_t)r * 64 + c]);
            if (relu) v = fmaxf(v, 0.f);
            out[(size_t)r * 64 + c] = __float2half_rn(v);
        }
    }
}

// ===========================================================================
// combine v11 (scalar path, kept for all non-64x64 shapes)
// ===========================================================================
template <int CIN, int COUT>
__global__ __launch_bounds__(256) void combine_kernel(
    const __half* T0, const __half* T1, const __half* T2, const __half* T3,
    const float* __restrict__ W, const float* __restrict__ bias,
    const __half* res, const __half* sc, const float* __restrict__ Wsc,
    __half* out, int relu, int V) {
    constexpr int SL    = CIN / 8;               // float4 slots per row
    constexpr int BURST = (SL < 4) ? SL : 4;     // 4 float4 = one 64B sector
    constexpr int NB    = SL / BURST;
    constexpr int SLS   = 32 / 8;                // shortcut always 32ch
    union U4 { float4 raw; __half2 h[4]; };
    union UW { float4 raw; v2f p[2]; };

    int g = blockIdx.x * 256 + threadIdx.x;
    if (g >= V * 8) return;

    v2f acc[COUT / 2];
    #pragma unroll
    for (int c = 0; c < COUT / 2; ++c) {
        if (bias) { acc[c].x = bias[2 * c]; acc[c].y = bias[2 * c + 1]; }
        else      { acc[c].x = 0.f;         acc[c].y = 0.f; }
    }

    auto rank1 = [&](float2 a, const float* w0f, const float* w1f) {
        v2f ax = {a.x, a.x}, ay = {a.y, a.y};
        if constexpr (COUT % 4 == 0) {
            const float4* w0 = (const float4*)w0f;
            const float4* w1 = (const float4*)w1f;
            #pragma unroll
            for (int cw = 0; cw < COUT / 4; ++cw) {
                UW A; A.raw = w0[cw];
                UW B; B.raw = w1[cw];
                acc[2 * cw]     = vfma2(ax, A.p[0], acc[2 * cw]);
                acc[2 * cw]     = vfma2(ay, B.p[0], acc[2 * cw]);
                acc[2 * cw + 1] = vfma2(ax, A.p[1], acc[2 * cw + 1]);
                acc[2 * cw + 1] = vfma2(ay, B.p[1], acc[2 * cw + 1]);
            }
        } else {
            const v2f* w0 = (const v2f*)w0f;
            const v2f* w1 = (const v2f*)w1f;
            #pragma unroll
            for (int c = 0; c < COUT / 2; ++c) {
                acc[c] = vfma2(ax, w0[c], acc[c]);
                acc[c] = vfma2(ay, w1[c], acc[c]);
            }
        }
    };

    const __half* Ts[4] = {T0, T1, T2, T3};
    #pragma unroll 1
    for (int k = 0; k < 4; ++k) {
        const float4* rp = (const float4*)(Ts[k] + (size_t)g * CIN);
        const float* Wk = W + (size_t)k * CIN * COUT;
        #pragma unroll 1
        for (int b2 = 0; b2 < NB; ++b2) {
            U4 x[BURST];
            #pragma unroll
            for (int j = 0; j < BURST; ++j) x[j].raw = rp[b2 * BURST + j];
            #pragma unroll
            for (int j = 0; j < BURST; ++j) {
                #pragma unroll
                for (int s = 0; s < 4; ++s) {
                    int q = (b2 * BURST + j) * 4 + s;
                    float2 a = __half22float2(x[j].h[s]);
                    rank1(a, Wk + (size_t)(2 * q) * COUT,
                             Wk + (size_t)(2 * q + 1) * COUT);
                }
            }
        }
    }
    if (sc) {
        const float4* sp = (const float4*)(sc + (size_t)g * 32);
        U4 x[SLS];
        #pragma unroll
        for (int j = 0; j < SLS; ++j) x[j].raw = sp[j];
        #pragma unroll
        for (int j = 0; j < SLS; ++j) {
            #pragma unroll
            for (int s = 0; s < 4; ++s) {
                int q = j * 4 + s;
                float2 a = __half22float2(x[j].h[s]);
                rank1(a, Wsc + (size_t)(2 * q) * COUT,
                         Wsc + (size_t)(2 * q + 1) * COUT);
            }
        }
    }

    size_t ob = (size_t)g * COUT;
    if constexpr (COUT % 8 == 0) {
        if (res) {
            const float4* rr = (const float4*)(res + ob);
            #pragma unroll
            for (int q = 0; q < COUT / 8; ++q) {
                U4 rv; rv.raw = rr[q];
                #pragma unroll
                for (int s = 0; s < 4; ++s) {
                    float2 f = __half22float2(rv.h[s]);
                    acc[q * 4 + s].x += f.x; acc[q * 4 + s].y += f.y;
                }
            }
        }
        if (relu) {
            #pragma unroll
            for (int c = 0; c < COUT / 2; ++c) {
                acc[c].x = fmaxf(acc[c].x, 0.f);
                acc[c].y = fmaxf(acc[c].y, 0.f);
            }
        }
        float4* ro = (float4*)(out + ob);
        #pragma unroll
        for (int q = 0; q < COUT / 8; ++q) {
            U4 o;
            #pragma unroll
            for (int s = 0; s < 4; ++s)
                o.h[s] = __floats2half2_rn(acc[q * 4 + s].x, acc[q * 4 + s].y);
            ro[q] = o.raw;
        }
    } else {
        if (res) {
            const __half2* rr = (const __half2*)(res + ob);
            #pragma unroll
            for (int c = 0; c < COUT / 2; ++c) {
                float2 f = __half22float2(rr[c]);
                acc[c].x += f.x; acc[c].y += f.y;
            }
        }
        if (relu) {
            #pragma unroll
            for (int c = 0; c < COUT / 2; ++c) {
                acc[c].x = fmaxf(acc[c].x, 0.f);
                acc[c].y = fmaxf(acc[c].y, 0.f);
            }
        }
        __half2* ro = (__half2*)(out + ob);
        #pragma unroll
        for (int c = 0; c < COUT / 2; ++c)
            ro[c] = __floats2half2_rn(acc[c].x, acc[c].y);
    }
}

// ===========================================================================
// BatchNorm: two-stage deterministic stats (no float atomics), SB=512.
// ===========================================================================
__global__ void bn_stats_part_kernel(const __half2* __restrict__ x2, int C, int relu_in,
                                     float* __restrict__ part, size_t N2) {
    __shared__ float sx[256], qx[256], sy[256], qy[256];
    int t = threadIdx.x;
    size_t i0 = (size_t)blockIdx.x * 256 + t;
    size_t step = (size_t)gridDim.x * 256;
    float ax = 0.f, aqx = 0.f, ay = 0.f, aqy = 0.f;
    for (size_t i = i0; i < N2; i += step) {
        float2 f = __half22float2(x2[i]);
        if (relu_in) { f.x = fmaxf(f.x, 0.f); f.y = fmaxf(f.y, 0.f); }
        ax += f.x; aqx += f.x * f.x;
        ay += f.y; aqy += f.y * f.y;
    }
    sx[t] = ax; qx[t] = aqx; sy[t] = ay; qy[t] = aqy;
    __syncthreads();
    int half = C >> 1;
    for (int st = 128; st >= half; st >>= 1) {
        if (t < st) {
            sx[t] += sx[t + st]; qx[t] += qx[t + st];
            sy[t] += sy[t + st]; qy[t] += qy[t + st];
        }
        __syncthreads();
    }
    if (t < half) {
        part[blockIdx.x * 128 + 2 * t]         = sx[t];
        part[blockIdx.x * 128 + 2 * t + 1]     = sy[t];
        part[blockIdx.x * 128 + C + 2 * t]     = qx[t];
        part[blockIdx.x * 128 + C + 2 * t + 1] = qy[t];
    }
}

__global__ void bn_reduce_kernel(const float* __restrict__ part, int nblk,
                                 const float* __restrict__ g, const float* __restrict__ be,
                                 float* __restrict__ ss, int C, float invN) {
    int c = threadIdx.x;
    if (c < C) {
        float s = 0.f, q = 0.f;
        for (int b = 0; b < nblk; ++b) {        // fixed order -> deterministic
            s += part[b * 128 + c];
            q += part[b * 128 + C + c];
        }
        float m = s * invN;
        float var = q * invN - m * m;
        float sc = g[c] * rsqrtf(var + 1e-5f);
        ss[c] = sc;
        ss[C + c] = be[c] - m * sc;
    }
}

// in-place: x = f(x)*a + b, f = relu if relu_in. float4-vectorized.
__global__ void affine_h_kernel(__half* x, const float* __restrict__ ss, int C,
                                int relu_in, size_t N2) {
    union U4 { float4 raw; __half2 h[4]; };
    size_t NG = N2 >> 2;
    size_t stride = (size_t)gridDim.x * blockDim.x;
    size_t i0 = (size_t)blockIdx.x * blockDim.x + threadIdx.x;
    float4* x4 = (float4*)x;
    int c0 = (int)((8 * i0) & (size_t)(C - 1));
    float sc[8], of[8];
    #pragma unroll
    for (int j = 0; j < 8; ++j) { sc[j] = ss[c0 + j]; of[j] = ss[C + c0 + j]; }
    for (size_t i = i0; i < NG; i += stride) {
        U4 u; u.raw = x4[i];
        #pragma unroll
        for (int j = 0; j < 4; ++j) {
            float2 f = __half22float2(u.h[j]);
            if (relu_in) { f.x = fmaxf(f.x, 0.f); f.y = fmaxf(f.y, 0.f); }
            f.x = f.x * sc[2 * j] + of[2 * j];
            f.y = f.y * sc[2 * j + 1] + of[2 * j + 1];
            u.h[j] = __floats2half2_rn(f.x, f.y);
        }
        x4[i] = u.raw;
    }
}

// ===========================================================================
// head: partial max + int-atomicMax, then log_softmax
// ===========================================================================
__global__ void maxpool_h_kernel(const __half* __restrict__ x, float* pooled, int V, int NS) {
    __shared__ float red[256];
    int o = blockIdx.x % 80;
    int slice = blockIdx.x / 80;
    int v0 = (int)((long long)V * slice / NS);
    int v1 = (int)((long long)V * (slice + 1) / NS);
    float m = 0.f;
    for (int v = v0 + threadIdx.x; v < v1; v += 256)
        m = fmaxf(m, __half2float(x[(size_t)v * 80 + o]));
    red[threadIdx.x] = m;
    __syncthreads();
    for (int st = 128; st > 0; st >>= 1) {
        if (threadIdx.x < st) red[threadIdx.x] = fmaxf(red[threadIdx.x], red[threadIdx.x + st]);
        __syncthreads();
    }
    if (threadIdx.x == 0) atomicMax((int*)&pooled[o], __float_as_int(red[0]));
}

__global__ void lsm_kernel(const float* __restrict__ pooled, float* __restrict__ out) {
    int b = threadIdx.x;
    if (b < 8) {
        float m = -1e30f;
        for (int c = 0; c < 10; ++c) m = fmaxf(m, pooled[b * 10 + c]);
        float s = 0.f;
        for (int c = 0; c < 10; ++c) s += expf(pooled[b * 10 + c] - m);
        float l = logf(s);
        for (int c = 0; c < 10; ++c)
            out[b * 10 + c] = pooled[b * 10 + c] - m - l;
    }
}

__global__ void encode_kernel(float* out, float val) {
    int i = threadIdx.x;
    if (i < 80) out[i] = val;
}

// ===========================================================================
// entry
// ===========================================================================
extern "C" void kernel_launch(void* const* d_in, const int* in_sizes, int n_in,
                              void* d_out, int out_size, void* d_ws, size_t ws_size,
                              hipStream_t stream) {
    (void)in_sizes; (void)n_in; (void)out_size;
    const int V = 50000, E = 800000;
    const int NCH = (V + 255) / 256;
    const int SB = 512;                       // bn stage-1 blocks
    const int NS = 8;                         // maxpool node slices

    auto al = [](size_t x) { return (x + 255) & ~(size_t)255; };
    const size_t FB = al((size_t)V * 512 * sizeof(__half));     // 51.2 MB
    const size_t WPB = al((size_t)256 * 64 * 2) * 2 + al((size_t)32 * 64 * 2) * 2;
    const size_t need = 5 * FB + al((V + 1) * 4) + al(V * 4) + al(E * 4) + al(E * 4)
                      + al((size_t)SB * 128 * 4) + al(8 * 128 * 4) + al(80 * 4) + al(NCH * 4)
                      + WPB;
    if (ws_size < need) {
        encode_kernel<<<1, 128, 0, stream>>>((float*)d_out, (float)(ws_size >> 20));
        return;
    }

    const float* x_in = (const float*)d_in[0];
    const int* rows   = (const int*)d_in[1];
    const int* colsi  = (const int*)d_in[2];
    const float* lvals = (const float*)d_in[3];
    const float* W_in = (const float*)d_in[4];
    const float* b_in = (const float*)d_in[5];
    const float* g1a = (const float*)d_in[6],  *be1a = (const float*)d_in[7];
    const float* W1a = (const float*)d_in[8],  *b1a  = (const float*)d_in[9];
    const float* g1b = (const float*)d_in[10], *be1b = (const float*)d_in[11];
    const float* W1b = (const float*)d_in[12], *b1b  = (const float*)d_in[13];
    const float* g2a = (const float*)d_in[14], *be2a = (const float*)d_in[15];
    const float* W2a = (const float*)d_in[16], *b2a  = (const float*)d_in[17];
    const float* g2b = (const float*)d_in[18], *be2b = (const float*)d_in[19];
    const float* W2b = (const float*)d_in[20], *b2b  = (const float*)d_in[21];
    const float* W2s = (const float*)d_in[22];
    const float* g3a = (const float*)d_in[23], *be3a = (const float*)d_in[24];
    const float* W3a = (const float*)d_in[25], *b3a  = (const float*)d_in[26];
    const float* g3b = (const float*)d_in[27], *be3b = (const float*)d_in[28];
    const float* W3b = (const float*)d_in[29], *b3b  = (const float*)d_in[30];
    const float* g_o = (const float*)d_in[31], *be_o = (const float*)d_in[32];
    const float* W_o = (const float*)d_in[33], *b_o  = (const float*)d_in[34];

    char* wp = (char*)d_ws;
    auto take = [&](size_t bytes) -> void* { void* p = (void*)wp; wp += al(bytes); return p; };
    __half* P0 = (__half*)take(FB);
    __half* P1 = (__half*)take(FB);
    __half* P2 = (__half*)take(FB);
    __half* P3 = (__half*)take(FB);
    __half* P4 = (__half*)take(FB);
    int* row_ptr  = (int*)take((V + 1) * sizeof(int));
    int* cursor   = (int*)take(V * sizeof(int));
    int* cols_s   = (int*)take(E * sizeof(int));
    float* vals_s = (float*)take(E * sizeof(float));
    float* part   = (float*)take((size_t)SB * 128 * sizeof(float));
    float* aff    = (float*)take(8 * 128 * sizeof(float));
    float* pooled = (float*)take(80 * sizeof(float));
    int* chunks   = (int*)take(NCH * sizeof(int));
    __half* wbh   = (__half*)take((size_t)256 * 64 * 2);
    __half* wbl   = (__half*)take((size_t)256 * 64 * 2);
    __half* wsh   = (__half*)take((size_t)32 * 64 * 2);
    __half* wsl   = (__half*)take((size_t)32 * 64 * 2);

    hipMemsetAsync(cursor, 0, V * sizeof(int), stream);
    hipMemsetAsync(pooled, 0, 80 * sizeof(float), stream);

    // ---- CSR build (+canonical row order) + input transpose ----
    hist_kernel<<<(E + 255) / 256, 256, 0, stream>>>(rows, cursor, E);
    chunk_sum_kernel<<<NCH, 256, 0, stream>>>(cursor, chunks, V);
    scan_chunks_kernel<<<1, 256, 0, stream>>>(chunks, NCH);
    scan_final_kernel<<<NCH, 256, 0, stream>>>(cursor, chunks, row_ptr, V);
    init_cursor_kernel<<<(V + 255) / 256, 256, 0, stream>>>(row_ptr, cursor, V);
    scatter_kernel<<<(E + 255) / 256, 256, 0, stream>>>(rows, colsi, lvals, cursor, cols_s, vals_s, E);
    sort_rows_kernel<<<(V + 255) / 256, 256, 0, stream>>>(row_ptr, cols_s, vals_s, V);
    transpose_in_kernel<<<4096, 256, 0, stream>>>(x_in, P0, V);

    // ---- helpers ----
    const int SG = (V + 3) / 4;
    auto spmm = [&](const __half* src, __half* dst, const __half* prev, int C) {
        if (C == 16)
            spmm2_kernel<1><<<SG, 256, 0, stream>>>(row_ptr, cols_s, vals_s,
                (const __half2*)src, (__half2*)dst, (const __half2*)prev, V);
        else if (C == 32)
            spmm2_kernel<2><<<SG, 256, 0, stream>>>(row_ptr, cols_s, vals_s,
                (const __half2*)src, (__half2*)dst, (const __half2*)prev, V);
        else
            spmm2_kernel<4><<<SG, 256, 0, stream>>>(row_ptr, cols_s, vals_s,
                (const __half2*)src, (__half2*)dst, (const __half2*)prev, V);
    };
    auto cheb3 = [&](const __half* a, __half* b, __half* c, __half* d, int C) {
        spmm(a, b, nullptr, C);
        spmm(b, c, a, C);
        spmm(c, d, b, C);
    };
    const int MG = (V * 8 + 255) / 256;
    auto comb = [&](const __half* T0, const __half* T1, const __half* T2, const __half* T3,
                    int Cin, int Cout, const float* W, const float* bias,
                    const __half* res, const __half* sc, const float* Wsc,
                    __half* out, int relu) {
        if (Cin == 64 && Cout == 64) {
            wprep_kernel<<<(256 * 64 + 255) / 256, 256, 0, stream>>>(W, wbh, wbl, 256);
            if (sc) wprep_kernel<<<(32 * 64 + 255) / 256, 256, 0, stream>>>(Wsc, wsh, wsl, 32);
            combine64_mfma_kernel<<<(V * 8) / 64, 256, 0, stream>>>(
                T0, T1, T2, T3, wbh, wbl, bias, res, sc, wsh, wsl, out, relu, V);
        } else if (Cin == 16 && Cout == 32)
            combine_kernel<16, 32><<<MG, 256, 0, stream>>>(T0, T1, T2, T3, W, bias, res, sc, Wsc, out, relu, V);
        else if (Cin == 32 && Cout == 32)
            combine_kernel<32, 32><<<MG, 256, 0, stream>>>(T0, T1, T2, T3, W, bias, res, sc, Wsc, out, relu, V);
        else if (Cin == 32 && Cout == 64)
            combine_kernel<32, 64><<<MG, 256, 0, stream>>>(T0, T1, T2, T3, W, bias, res, sc, Wsc, out, relu, V);
        else
            combine_kernel<64, 10><<<MG, 256, 0, stream>>>(T0, T1, T2, T3, W, bias, res, sc, Wsc, out, relu, V);
    };
    auto stats = [&](const __half* xb, int C, int relu, int slot, const float* g, const float* be) {
        bn_stats_part_kernel<<<SB, 256, 0, stream>>>((const __half2*)xb, C, relu, part,
                                                     (size_t)V * 4 * C);
        bn_reduce_kernel<<<1, 64, 0, stream>>>(part, SB, g, be, aff + slot * 128, C,
                                               1.f / ((float)V * 8.f));
    };
    auto affine = [&](__half* xb, int C, int relu, int slot) {
        affine_h_kernel<<<2048, 256, 0, stream>>>(xb, aff + slot * 128, C, relu,
                                                  (size_t)V * 4 * C);
    };
    const __half* NH = nullptr;
    const float*  NF = nullptr;

    // ---- conv_in: x=P0 (16ch) -> relu(cheb+b) -> P4 (32ch) ----
    cheb3(P0, P1, P2, P3, 16);
    comb(P0, P1, P2, P3, 16, 32, W_in, b_in, NH, NH, NF, P4, 1);

    // ---- block 1 (X=P4, 32ch, identity shortcut) ----
    stats(P4, 32, 0, 0, g1a, be1a);
    affine(P4, 32, 0, 0);                   // P4 = xn
    cheb3(P4, P0, P1, P2, 32);
    comb(P4, P0, P1, P2, 32, 32, W1a, b1a, NH, NH, NF, P0, 0);   // out_a = P0
    stats(P0, 32, 1, 1, g1b, be1b);
    affine(P0, 32, 1, 1);                   // P0 = y
    cheb3(P0, P1, P2, P3, 32);
    comb(P0, P1, P2, P3, 32, 32, W1b, b1b, P4, NH, NF, P4, 1);   // P4 = block1 out

    // ---- block 2 (X=P4, 32ch -> 64ch, W2s shortcut) ----
    stats(P4, 32, 0, 2, g2a, be2a);
    affine(P4, 32, 0, 2);                   // P4 = xn (32ch)
    cheb3(P4, P0, P1, P2, 32);
    comb(P4, P0, P1, P2, 32, 64, W2a, b2a, NH, NH, NF, P3, 0);   // out_a = P3 (64ch)
    stats(P3, 64, 1, 3, g2b, be2b);
    affine(P3, 64, 1, 3);                   // P3 = y
    cheb3(P3, P0, P1, P2, 64);
    comb(P3, P0, P1, P2, 64, 64, W2b, b2b, NH, P4, W2s, P0, 1);  // P0 = block2 out (MFMA)

    // ---- block 3 (X=P0, 64ch, identity shortcut) ----
    stats(P0, 64, 0, 4, g3a, be3a);
    affine(P0, 64, 0, 4);                   // P0 = xn
    cheb3(P0, P1, P2, P3, 64);
    comb(P0, P1, P2, P3, 64, 64, W3a, b3a, NH, NH, NF, P1, 0);   // out_a = P1 (MFMA)
    stats(P1, 64, 1, 5, g3b, be3b);
    affine(P1, 64, 1, 5);                   // P1 = y
    cheb3(P1, P2, P3, P4, 64);
    comb(P1, P2, P3, P4, 64, 64, W3b, b3b, P0, NH, NF, P1, 1);   // P1 = block3 out (MFMA)

    // ---- head: bn -> relu(cheb 64->10) -> maxpool -> log_softmax ----
    stats(P1, 64, 0, 6, g_o, be_o);
    affine(P1, 64, 0, 6);                   // P1 = bn(x)
    cheb3(P1, P0, P2, P3, 64);
    comb(P1, P0, P2, P3, 64, 10, W_o, b_o, NH, NH, NF, P4, 1);   // P4 = 80-wide logits
    maxpool_h_kernel<<<80 * NS, 256, 0, stream>>>(P4, pooled, V, NS);
    lsm_kernel<<<1, 64, 0, stream>>>(pooled, (float*)d_out);
}

// Round 15
// 4244.514 us; speedup vs baseline: 1.0588x; 1.0588x over previous
//
#include <hip/hip_runtime.h>
#include <hip/hip_bf16.h>
#include <hip/hip_fp16.h>

// packed fp32 pair — __builtin_elementwise_fma ONLY (round-11: asm FMA 2x
// regression; round-12: float4 W loads neutral -> compiler already optimal).
typedef float v2f __attribute__((ext_vector_type(2)));
__device__ __forceinline__ v2f vfma2(v2f a, v2f b, v2f c) {
#if __has_builtin(__builtin_elementwise_fma)
    return __builtin_elementwise_fma(a, b, c);
#else
    v2f d; d.x = fmaf(a.x, b.x, c.x); d.y = fmaf(a.y, b.y, c.y); return d;
#endif
}

// MFMA vector types (ext vectors, NOT HIP structs)
typedef _Float16 half8v __attribute__((ext_vector_type(8)));
typedef float    f32x4  __attribute__((ext_vector_type(4)));

// ===========================================================================
// CSR build (multi-block scan; deterministic via per-row sort)
// ===========================================================================
__global__ void hist_kernel(const int* __restrict__ rows, int* __restrict__ counts, int E) {
    int i = blockIdx.x * blockDim.x + threadIdx.x;
    if (i < E) atomicAdd(&counts[rows[i]], 1);
}

__global__ void chunk_sum_kernel(const int* __restrict__ counts, int* __restrict__ chunk_sums, int V) {
    __shared__ int sh[256];
    int t = threadIdx.x;
    int i = blockIdx.x * 256 + t;
    sh[t] = (i < V) ? counts[i] : 0;
    __syncthreads();
    for (int st = 128; st > 0; st >>= 1) {
        if (t < st) sh[t] += sh[t + st];
        __syncthreads();
    }
    if (t == 0) chunk_sums[blockIdx.x] = sh[0];
}

__global__ void scan_chunks_kernel(int* __restrict__ cs, int n) {
    __shared__ int wsum[4];
    int t = threadIdx.x, lane = t & 63, w = t >> 6;
    int orig = (t < n) ? cs[t] : 0;
    int x = orig;
    #pragma unroll
    for (int d = 1; d < 64; d <<= 1) {
        int y = __shfl_up(x, d);
        if (lane >= d) x += y;
    }
    if (lane == 63) wsum[w] = x;
    __syncthreads();
    int wo = 0;
    for (int j = 0; j < w; ++j) wo += wsum[j];
    if (t < n) cs[t] = wo + x - orig;     // exclusive
}

__global__ void scan_final_kernel(const int* __restrict__ counts, const int* __restrict__ chunk_off,
                                  int* __restrict__ row_ptr, int V) {
    __shared__ int wsum[4];
    int t = threadIdx.x, lane = t & 63, w = t >> 6;
    int i = blockIdx.x * 256 + t;
    int x = (i < V) ? counts[i] : 0;
    #pragma unroll
    for (int d = 1; d < 64; d <<= 1) {
        int y = __shfl_up(x, d);
        if (lane >= d) x += y;
    }
    if (lane == 63) wsum[w] = x;
    __syncthreads();
    int wo = 0;
    for (int j = 0; j < w; ++j) wo += wsum[j];
    if (i < V) row_ptr[i + 1] = chunk_off[blockIdx.x] + wo + x;
    if (i == 0) row_ptr[0] = 0;
}

__global__ void init_cursor_kernel(const int* __restrict__ row_ptr, int* __restrict__ cursor, int V) {
    int i = blockIdx.x * blockDim.x + threadIdx.x;
    if (i < V) cursor[i] = row_ptr[i];
}

__global__ void scatter_kernel(const int* __restrict__ rows, const int* __restrict__ cols,
                               const float* __restrict__ vals, int* __restrict__ cursor,
                               int* __restrict__ cols_s, float* __restrict__ vals_s, int E) {
    int i = blockIdx.x * blockDim.x + threadIdx.x;
    if (i < E) {
        int r = rows[i];
        int p = atomicAdd(&cursor[r], 1);
        cols_s[p] = cols[i];
        vals_s[p] = vals[i];
    }
}

// canonical per-row order: insertion sort by (col, val-bits). Makes CSR
// bitwise-deterministic regardless of scatter's atomic ordering.
__global__ void sort_rows_kernel(const int* __restrict__ row_ptr, int* cols, float* vals, int V) {
    int v = blockIdx.x * blockDim.x + threadIdx.x;
    if (v >= V) return;
    int e0 = row_ptr[v], e1 = row_ptr[v + 1];
    for (int i = e0 + 1; i < e1; ++i) {
        int c = cols[i];
        unsigned xb = __float_as_uint(vals[i]);
        int j = i - 1;
        while (j >= e0) {
            int cj = cols[j];
            unsigned vj = __float_as_uint(vals[j]);
            if (cj > c || (cj == c && vj > xb)) {
                cols[j + 1] = cj; vals[j + 1] = __uint_as_float(vj);
                --j;
            } else break;
        }
        cols[j + 1] = c;
        vals[j + 1] = __uint_as_float(xb);
    }
}

// ===========================================================================
// transpose input (B,16,V) fp32 -> (V, B*16) fp16
// ===========================================================================
__global__ void transpose_in_kernel(const float* __restrict__ x, __half* __restrict__ X, int V) {
    int total = V * 128;
    for (int i = blockIdx.x * blockDim.x + threadIdx.x; i < total; i += gridDim.x * blockDim.x) {
        int v = i >> 7;
        int t = i & 127;          // t = b*16 + c
        X[i] = __float2half(x[t * V + v]);
    }
}

// ===========================================================================
// SpMM (parked: round-10 A/B showed batch-split neutral). One wave per node;
// 8-deep edge unroll.
// ===========================================================================
template <int VPT> struct PackT;
template <> struct PackT<1> { using T = float;  };
template <> struct PackT<2> { using T = float2; };
template <> struct PackT<4> { using T = float4; };

template <int VPT>
__global__ __launch_bounds__(256) void spmm2_kernel(
    const int* __restrict__ row_ptr, const int* __restrict__ cols,
    const float* __restrict__ vals, const __half2* __restrict__ src,
    __half2* dst, const __half2* prev, int V) {
    using T = typename PackT<VPT>::T;
    union U { T raw; __half2 h[VPT]; };
    int lane = threadIdx.x & 63;
    int v = (blockIdx.x << 2) | (threadIdx.x >> 6);
    if (v >= V) return;
    const int W = VPT * 64;
    const size_t row = (size_t)v * W + lane * VPT;

    float pr[2 * VPT];
    bool hasp = (prev != nullptr);
    if (hasp) {
        U pv; pv.raw = *(const T*)(prev + row);
        #pragma unroll
        for (int j = 0; j < VPT; ++j) {
            float2 f = __half22float2(pv.h[j]);
            pr[2 * j] = f.x; pr[2 * j + 1] = f.y;
        }
    }
    float acc[2 * VPT];
    #pragma unroll
    for (int j = 0; j < 2 * VPT; ++j) acc[j] = 0.f;

    int e0 = row_ptr[v], e1 = row_ptr[v + 1];
    int e = e0;
    for (; e + 8 <= e1; e += 8) {
        int   c[8]; float w[8]; U g[8];
        #pragma unroll
        for (int k = 0; k < 8; ++k) { c[k] = cols[e + k]; w[k] = vals[e + k]; }
        #pragma unroll
        for (int k = 0; k < 8; ++k)
            g[k].raw = *(const T*)(src + (size_t)c[k] * W + lane * VPT);
        #pragma unroll
        for (int k = 0; k < 8; ++k) {
            #pragma unroll
            for (int j = 0; j < VPT; ++j) {
                float2 f = __half22float2(g[k].h[j]);
                acc[2*j] += w[k] * f.x; acc[2*j+1] += w[k] * f.y;
            }
        }
    }
    for (; e + 4 <= e1; e += 4) {
        int   c[4]; float w[4]; U g[4];
        #pragma unroll
        for (int k = 0; k < 4; ++k) { c[k] = cols[e + k]; w[k] = vals[e + k]; }
        #pragma unroll
        for (int k = 0; k < 4; ++k)
            g[k].raw = *(const T*)(src + (size_t)c[k] * W + lane * VPT);
        #pragma unroll
        for (int k = 0; k < 4; ++k) {
            #pragma unroll
            for (int j = 0; j < VPT; ++j) {
                float2 f = __half22float2(g[k].h[j]);
                acc[2*j] += w[k] * f.x; acc[2*j+1] += w[k] * f.y;
            }
        }
    }
    for (; e < e1; ++e) {
        int c = cols[e]; float wv = vals[e];
        U g; g.raw = *(const T*)(src + (size_t)c * W + lane * VPT);
        #pragma unroll
        for (int j = 0; j < VPT; ++j) {
            float2 f = __half22float2(g.h[j]);
            acc[2*j] += wv * f.x; acc[2*j+1] += wv * f.y;
        }
    }
    if (hasp) {
        #pragma unroll
        for (int j = 0; j < 2 * VPT; ++j) acc[j] = 2.f * acc[j] - pr[j];
    }
    U o;
    #pragma unroll
    for (int j = 0; j < VPT; ++j) o.h[j] = __floats2half2_rn(acc[2*j], acc[2*j+1]);
    *(T*)(dst + row) = o.raw;
}

// ===========================================================================
// W prep for MFMA combine: W[kt][co] fp32 -> Bh/Bl[co][kt] fp16 two-term
// split. Transposed so B-fragments are contiguous 16B loads.
// ===========================================================================
__global__ void wprep_kernel(const float* __restrict__ W, __half* __restrict__ Bh,
                             __half* __restrict__ Bl, int KT) {
    int i = blockIdx.x * 256 + threadIdx.x;
    if (i >= KT * 64) return;
    int kt = i >> 6, co = i & 63;
    float w = W[(size_t)kt * 64 + co];
    __half h = __float2half_rn(w);
    Bh[(size_t)co * KT + kt] = h;
    Bl[(size_t)co * KT + kt] = __float2half_rn(w - __half2float(h));
}

// ===========================================================================
// combine64 via MFMA, v3 (round-15): rounds 13/14 pinned at ~230us with ALL
// pipes idle; leading suspect = per-wave B-stream (every wave re-reads the
// full 64KB Bh+Bl from L2 -> 3.2GB L2 traffic + 64 dependent load->MFMA
// chains). v3: each wave computes 32 ROWS (two 16-row tiles) -> every B
// fragment feeds 4 MFMAs (2 tiles x h/l): per-output B traffic and B-load
// count HALVED, MFMA:load ratio doubled. A loaded in-loop (r14's preload
// array regressed occupancy). Per-output-element MFMA chain order unchanged
// (s asc, ct asc, h then l) -> bitwise identical to r13/r14.
// Aliasing: out may alias T1; each wave reads its 32-row range before
// writing it; ranges disjoint across waves.
// ===========================================================================
__global__ __launch_bounds__(256) void combine64_mfma_kernel(
    const __half* T0, const __half* T1, const __half* T2, const __half* T3,
    const __half* __restrict__ Bh, const __half* __restrict__ Bl,
    const float* __restrict__ bias,
    const __half* res, const __half* sc,
    const __half* __restrict__ Bsh, const __half* __restrict__ Bsl,
    __half* out, int relu, int V) {
    int l   = threadIdx.x & 63;
    int wid = threadIdx.x >> 6;
    int row0 = blockIdx.x * 128 + wid * 32;      // wave owns rows [row0, row0+32)
    if (row0 >= V * 8) return;
    int lr = l & 15, lg = l >> 4;

    f32x4 acc0[4], acc1[4];
    #pragma unroll
    for (int ct = 0; ct < 4; ++ct) {
        float b = bias ? bias[ct * 16 + lr] : 0.f;
        acc0[ct] = (f32x4){b, b, b, b};
        acc1[ct] = (f32x4){b, b, b, b};
    }

    const __half* Ts[4] = {T0, T1, T2, T3};
    #pragma unroll
    for (int s = 0; s < 8; ++s) {
        const __half* tb = Ts[s >> 1];
        size_t ao = (size_t)(row0 + lr) * 64 + (s & 1) * 32 + lg * 8;
        half8v a0 = *(const half8v*)(tb + ao);
        half8v a1 = *(const half8v*)(tb + ao + 16 * 64);
        #pragma unroll
        for (int ct = 0; ct < 4; ++ct) {
            half8v bh = *(const half8v*)(Bh + (size_t)(ct * 16 + lr) * 256 + s * 32 + lg * 8);
            half8v bl = *(const half8v*)(Bl + (size_t)(ct * 16 + lr) * 256 + s * 32 + lg * 8);
            acc0[ct] = __builtin_amdgcn_mfma_f32_16x16x32_f16(a0, bh, acc0[ct], 0, 0, 0);
            acc0[ct] = __builtin_amdgcn_mfma_f32_16x16x32_f16(a0, bl, acc0[ct], 0, 0, 0);
            acc1[ct] = __builtin_amdgcn_mfma_f32_16x16x32_f16(a1, bh, acc1[ct], 0, 0, 0);
            acc1[ct] = __builtin_amdgcn_mfma_f32_16x16x32_f16(a1, bl, acc1[ct], 0, 0, 0);
        }
    }
    if (sc) {                                   // 32-ch shortcut, single K-slice
        size_t so = (size_t)(row0 + lr) * 32 + lg * 8;
        half8v a20 = *(const half8v*)(sc + so);
        half8v a21 = *(const half8v*)(sc + so + 16 * 32);
        #pragma unroll
        for (int ct = 0; ct < 4; ++ct) {
            half8v bh = *(const half8v*)(Bsh + (size_t)(ct * 16 + lr) * 32 + lg * 8);
            half8v bl = *(const half8v*)(Bsl + (size_t)(ct * 16 + lr) * 32 + lg * 8);
            acc0[ct] = __builtin_amdgcn_mfma_f32_16x16x32_f16(a20, bh, acc0[ct], 0, 0, 0);
            acc0[ct] = __builtin_amdgcn_mfma_f32_16x16x32_f16(a20, bl, acc0[ct], 0, 0, 0);
            acc1[ct] = __builtin_amdgcn_mfma_f32_16x16x32_f16(a21, bh, acc1[ct], 0, 0, 0);
            acc1[ct] = __builtin_amdgcn_mfma_f32_16x16x32_f16(a21, bl, acc1[ct], 0, 0, 0);
        }
    }

    #pragma unroll
    for (int rt = 0; rt < 2; ++rt) {
        f32x4* acc = rt ? acc1 : acc0;
        #pragma unroll
        for (int ct = 0; ct < 4; ++ct) {
            #pragma unroll
            for (int j = 0; j < 4; ++j) {
                int r = row0 + rt * 16 + lg * 4 + j;
                int c = ct * 16 + lr;
                float v = acc[ct][j];
                if (res) v += __half2float(res[(size_t)r * 64 + c]);
                if (relu) v = fmaxf(v, 0.f);
                out[(size_t)r * 64 + c] = __float2half_rn(v);
            }
        }
    }
}

// ===========================================================================
// combine v11 (scalar path, kept for all non-64x64 shapes)
// ===========================================================================
template <int CIN, int COUT>
__global__ __launch_bounds__(256) void combine_kernel(
    const __half* T0, const __half* T1, const __half* T2, const __half* T3,
    const float* __restrict__ W, const float* __restrict__ bias,
    const __half* res, const __half* sc, const float* __restrict__ Wsc,
    __half* out, int relu, int V) {
    constexpr int SL    = CIN / 8;               // float4 slots per row
    constexpr int BURST = (SL < 4) ? SL : 4;     // 4 float4 = one 64B sector
    constexpr int NB    = SL / BURST;
    constexpr int SLS   = 32 / 8;                // shortcut always 32ch
    union U4 { float4 raw; __half2 h[4]; };
    union UW { float4 raw; v2f p[2]; };

    int g = blockIdx.x * 256 + threadIdx.x;
    if (g >= V * 8) return;

    v2f acc[COUT / 2];
    #pragma unroll
    for (int c = 0; c < COUT / 2; ++c) {
        if (bias) { acc[c].x = bias[2 * c]; acc[c].y = bias[2 * c + 1]; }
        else      { acc[c].x = 0.f;         acc[c].y = 0.f; }
    }

    auto rank1 = [&](float2 a, const float* w0f, const float* w1f) {
        v2f ax = {a.x, a.x}, ay = {a.y, a.y};
        if constexpr (COUT % 4 == 0) {
            const float4* w0 = (const float4*)w0f;
            const float4* w1 = (const float4*)w1f;
            #pragma unroll
            for (int cw = 0; cw < COUT / 4; ++cw) {
                UW A; A.raw = w0[cw];
                UW B; B.raw = w1[cw];
                acc[2 * cw]     = vfma2(ax, A.p[0], acc[2 * cw]);
                acc[2 * cw]     = vfma2(ay, B.p[0], acc[2 * cw]);
                acc[2 * cw + 1] = vfma2(ax, A.p[1], acc[2 * cw + 1]);
                acc[2 * cw + 1] = vfma2(ay, B.p[1], acc[2 * cw + 1]);
            }
        } else {
            const v2f* w0 = (const v2f*)w0f;
            const v2f* w1 = (const v2f*)w1f;
            #pragma unroll
            for (int c = 0; c < COUT / 2; ++c) {
                acc[c] = vfma2(ax, w0[c], acc[c]);
                acc[c] = vfma2(ay, w1[c], acc[c]);
            }
        }
    };

    const __half* Ts[4] = {T0, T1, T2, T3};
    #pragma unroll 1
    for (int k = 0; k < 4; ++k) {
        const float4* rp = (const float4*)(Ts[k] + (size_t)g * CIN);
        const float* Wk = W + (size_t)k * CIN * COUT;
        #pragma unroll 1
        for (int b2 = 0; b2 < NB; ++b2) {
            U4 x[BURST];
            #pragma unroll
            for (int j = 0; j < BURST; ++j) x[j].raw = rp[b2 * BURST + j];
            #pragma unroll
            for (int j = 0; j < BURST; ++j) {
                #pragma unroll
                for (int s = 0; s < 4; ++s) {
                    int q = (b2 * BURST + j) * 4 + s;
                    float2 a = __half22float2(x[j].h[s]);
                    rank1(a, Wk + (size_t)(2 * q) * COUT,
                             Wk + (size_t)(2 * q + 1) * COUT);
                }
            }
        }
    }
    if (sc) {
        const float4* sp = (const float4*)(sc + (size_t)g * 32);
        U4 x[SLS];
        #pragma unroll
        for (int j = 0; j < SLS; ++j) x[j].raw = sp[j];
        #pragma unroll
        for (int j = 0; j < SLS; ++j) {
            #pragma unroll
            for (int s = 0; s < 4; ++s) {
                int q = j * 4 + s;
                float2 a = __half22float2(x[j].h[s]);
                rank1(a, Wsc + (size_t)(2 * q) * COUT,
                         Wsc + (size_t)(2 * q + 1) * COUT);
            }
        }
    }

    size_t ob = (size_t)g * COUT;
    if constexpr (COUT % 8 == 0) {
        if (res) {
            const float4* rr = (const float4*)(res + ob);
            #pragma unroll
            for (int q = 0; q < COUT / 8; ++q) {
                U4 rv; rv.raw = rr[q];
                #pragma unroll
                for (int s = 0; s < 4; ++s) {
                    float2 f = __half22float2(rv.h[s]);
                    acc[q * 4 + s].x += f.x; acc[q * 4 + s].y += f.y;
                }
            }
        }
        if (relu) {
            #pragma unroll
            for (int c = 0; c < COUT / 2; ++c) {
                acc[c].x = fmaxf(acc[c].x, 0.f);
                acc[c].y = fmaxf(acc[c].y, 0.f);
            }
        }
        float4* ro = (float4*)(out + ob);
        #pragma unroll
        for (int q = 0; q < COUT / 8; ++q) {
            U4 o;
            #pragma unroll
            for (int s = 0; s < 4; ++s)
                o.h[s] = __floats2half2_rn(acc[q * 4 + s].x, acc[q * 4 + s].y);
            ro[q] = o.raw;
        }
    } else {
        if (res) {
            const __half2* rr = (const __half2*)(res + ob);
            #pragma unroll
            for (int c = 0; c < COUT / 2; ++c) {
                float2 f = __half22float2(rr[c]);
                acc[c].x += f.x; acc[c].y += f.y;
            }
        }
        if (relu) {
            #pragma unroll
            for (int c = 0; c < COUT / 2; ++c) {
                acc[c].x = fmaxf(acc[c].x, 0.f);
                acc[c].y = fmaxf(acc[c].y, 0.f);
            }
        }
        __half2* ro = (__half2*)(out + ob);
        #pragma unroll
        for (int c = 0; c < COUT / 2; ++c)
            ro[c] = __floats2half2_rn(acc[c].x, acc[c].y);
    }
}

// ===========================================================================
// BatchNorm: two-stage deterministic stats (no float atomics), SB=512.
// ===========================================================================
__global__ void bn_stats_part_kernel(const __half2* __restrict__ x2, int C, int relu_in,
                                     float* __restrict__ part, size_t N2) {
    __shared__ float sx[256], qx[256], sy[256], qy[256];
    int t = threadIdx.x;
    size_t i0 = (size_t)blockIdx.x * 256 + t;
    size_t step = (size_t)gridDim.x * 256;
    float ax = 0.f, aqx = 0.f, ay = 0.f, aqy = 0.f;
    for (size_t i = i0; i < N2; i += step) {
        float2 f = __half22float2(x2[i]);
        if (relu_in) { f.x = fmaxf(f.x, 0.f); f.y = fmaxf(f.y, 0.f); }
        ax += f.x; aqx += f.x * f.x;
        ay += f.y; aqy += f.y * f.y;
    }
    sx[t] = ax; qx[t] = aqx; sy[t] = ay; qy[t] = aqy;
    __syncthreads();
    int half = C >> 1;
    for (int st = 128; st >= half; st >>= 1) {
        if (t < st) {
            sx[t] += sx[t + st]; qx[t] += qx[t + st];
            sy[t] += sy[t + st]; qy[t] += qy[t + st];
        }
        __syncthreads();
    }
    if (t < half) {
        part[blockIdx.x * 128 + 2 * t]         = sx[t];
        part[blockIdx.x * 128 + 2 * t + 1]     = sy[t];
        part[blockIdx.x * 128 + C + 2 * t]     = qx[t];
        part[blockIdx.x * 128 + C + 2 * t + 1] = qy[t];
    }
}

__global__ void bn_reduce_kernel(const float* __restrict__ part, int nblk,
                                 const float* __restrict__ g, const float* __restrict__ be,
                                 float* __restrict__ ss, int C, float invN) {
    int c = threadIdx.x;
    if (c < C) {
        float s = 0.f, q = 0.f;
        for (int b = 0; b < nblk; ++b) {        // fixed order -> deterministic
            s += part[b * 128 + c];
            q += part[b * 128 + C + c];
        }
        float m = s * invN;
        float var = q * invN - m * m;
        float sc = g[c] * rsqrtf(var + 1e-5f);
        ss[c] = sc;
        ss[C + c] = be[c] - m * sc;
    }
}

// in-place: x = f(x)*a + b, f = relu if relu_in. float4-vectorized.
__global__ void affine_h_kernel(__half* x, const float* __restrict__ ss, int C,
                                int relu_in, size_t N2) {
    union U4 { float4 raw; __half2 h[4]; };
    size_t NG = N2 >> 2;
    size_t stride = (size_t)gridDim.x * blockDim.x;
    size_t i0 = (size_t)blockIdx.x * blockDim.x + threadIdx.x;
    float4* x4 = (float4*)x;
    int c0 = (int)((8 * i0) & (size_t)(C - 1));
    float sc[8], of[8];
    #pragma unroll
    for (int j = 0; j < 8; ++j) { sc[j] = ss[c0 + j]; of[j] = ss[C + c0 + j]; }
    for (size_t i = i0; i < NG; i += stride) {
        U4 u; u.raw = x4[i];
        #pragma unroll
        for (int j = 0; j < 4; ++j) {
            float2 f = __half22float2(u.h[j]);
            if (relu_in) { f.x = fmaxf(f.x, 0.f); f.y = fmaxf(f.y, 0.f); }
            f.x = f.x * sc[2 * j] + of[2 * j];
            f.y = f.y * sc[2 * j + 1] + of[2 * j + 1];
            u.h[j] = __floats2half2_rn(f.x, f.y);
        }
        x4[i] = u.raw;
    }
}

// ===========================================================================
// head: partial max + int-atomicMax, then log_softmax
// ===========================================================================
__global__ void maxpool_h_kernel(const __half* __restrict__ x, float* pooled, int V, int NS) {
    __shared__ float red[256];
    int o = blockIdx.x % 80;
    int slice = blockIdx.x / 80;
    int v0 = (int)((long long)V * slice / NS);
    int v1 = (int)((long long)V * (slice + 1) / NS);
    float m = 0.f;
    for (int v = v0 + threadIdx.x; v < v1; v += 256)
        m = fmaxf(m, __half2float(x[(size_t)v * 80 + o]));
    red[threadIdx.x] = m;
    __syncthreads();
    for (int st = 128; st > 0; st >>= 1) {
        if (threadIdx.x < st) red[threadIdx.x] = fmaxf(red[threadIdx.x], red[threadIdx.x + st]);
        __syncthreads();
    }
    if (threadIdx.x == 0) atomicMax((int*)&pooled[o], __float_as_int(red[0]));
}

__global__ void lsm_kernel(const float* __restrict__ pooled, float* __restrict__ out) {
    int b = threadIdx.x;
    if (b < 8) {
        float m = -1e30f;
        for (int c = 0; c < 10; ++c) m = fmaxf(m, pooled[b * 10 + c]);
        float s = 0.f;
        for (int c = 0; c < 10; ++c) s += expf(pooled[b * 10 + c] - m);
        float l = logf(s);
        for (int c = 0; c < 10; ++c)
            out[b * 10 + c] = pooled[b * 10 + c] - m - l;
    }
}

__global__ void encode_kernel(float* out, float val) {
    int i = threadIdx.x;
    if (i < 80) out[i] = val;
}

// ===========================================================================
// entry
// ===========================================================================
extern "C" void kernel_launch(void* const* d_in, const int* in_sizes, int n_in,
                              void* d_out, int out_size, void* d_ws, size_t ws_size,
                              hipStream_t stream) {
    (void)in_sizes; (void)n_in; (void)out_size;
    const int V = 50000, E = 800000;
    const int NCH = (V + 255) / 256;
    const int SB = 512;                       // bn stage-1 blocks
    const int NS = 8;                         // maxpool node slices

    auto al = [](size_t x) { return (x + 255) & ~(size_t)255; };
    const size_t FB = al((size_t)V * 512 * sizeof(__half));     // 51.2 MB
    const size_t WPB = al((size_t)256 * 64 * 2) * 2 + al((size_t)32 * 64 * 2) * 2;
    const size_t need = 5 * FB + al((V + 1) * 4) + al(V * 4) + al(E * 4) + al(E * 4)
                      + al((size_t)SB * 128 * 4) + al(8 * 128 * 4) + al(80 * 4) + al(NCH * 4)
                      + WPB;
    if (ws_size < need) {
        encode_kernel<<<1, 128, 0, stream>>>((float*)d_out, (float)(ws_size >> 20));
        return;
    }

    const float* x_in = (const float*)d_in[0];
    const int* rows   = (const int*)d_in[1];
    const int* colsi  = (const int*)d_in[2];
    const float* lvals = (const float*)d_in[3];
    const float* W_in = (const float*)d_in[4];
    const float* b_in = (const float*)d_in[5];
    const float* g1a = (const float*)d_in[6],  *be1a = (const float*)d_in[7];
    const float* W1a = (const float*)d_in[8],  *b1a  = (const float*)d_in[9];
    const float* g1b = (const float*)d_in[10], *be1b = (const float*)d_in[11];
    const float* W1b = (const float*)d_in[12], *b1b  = (const float*)d_in[13];
    const float* g2a = (const float*)d_in[14], *be2a = (const float*)d_in[15];
    const float* W2a = (const float*)d_in[16], *b2a  = (const float*)d_in[17];
    const float* g2b = (const float*)d_in[18], *be2b = (const float*)d_in[19];
    const float* W2b = (const float*)d_in[20], *b2b  = (const float*)d_in[21];
    const float* W2s = (const float*)d_in[22];
    const float* g3a = (const float*)d_in[23], *be3a = (const float*)d_in[24];
    const float* W3a = (const float*)d_in[25], *b3a  = (const float*)d_in[26];
    const float* g3b = (const float*)d_in[27], *be3b = (const float*)d_in[28];
    const float* W3b = (const float*)d_in[29], *b3b  = (const float*)d_in[30];
    const float* g_o = (const float*)d_in[31], *be_o = (const float*)d_in[32];
    const float* W_o = (const float*)d_in[33], *b_o  = (const float*)d_in[34];

    char* wp = (char*)d_ws;
    auto take = [&](size_t bytes) -> void* { void* p = (void*)wp; wp += al(bytes); return p; };
    __half* P0 = (__half*)take(FB);
    __half* P1 = (__half*)take(FB);
    __half* P2 = (__half*)take(FB);
    __half* P3 = (__half*)take(FB);
    __half* P4 = (__half*)take(FB);
    int* row_ptr  = (int*)take((V + 1) * sizeof(int));
    int* cursor   = (int*)take(V * sizeof(int));
    int* cols_s   = (int*)take(E * sizeof(int));
    float* vals_s = (float*)take(E * sizeof(float));
    float* part   = (float*)take((size_t)SB * 128 * sizeof(float));
    float* aff    = (float*)take(8 * 128 * sizeof(float));
    float* pooled = (float*)take(80 * sizeof(float));
    int* chunks   = (int*)take(NCH * sizeof(int));
    __half* wbh   = (__half*)take((size_t)256 * 64 * 2);
    __half* wbl   = (__half*)take((size_t)256 * 64 * 2);
    __half* wsh   = (__half*)take((size_t)32 * 64 * 2);
    __half* wsl   = (__half*)take((size_t)32 * 64 * 2);

    hipMemsetAsync(cursor, 0, V * sizeof(int), stream);
    hipMemsetAsync(pooled, 0, 80 * sizeof(float), stream);

    // ---- CSR build (+canonical row order) + input transpose ----
    hist_kernel<<<(E + 255) / 256, 256, 0, stream>>>(rows, cursor, E);
    chunk_sum_kernel<<<NCH, 256, 0, stream>>>(cursor, chunks, V);
    scan_chunks_kernel<<<1, 256, 0, stream>>>(chunks, NCH);
    scan_final_kernel<<<NCH, 256, 0, stream>>>(cursor, chunks, row_ptr, V);
    init_cursor_kernel<<<(V + 255) / 256, 256, 0, stream>>>(row_ptr, cursor, V);
    scatter_kernel<<<(E + 255) / 256, 256, 0, stream>>>(rows, colsi, lvals, cursor, cols_s, vals_s, E);
    sort_rows_kernel<<<(V + 255) / 256, 256, 0, stream>>>(row_ptr, cols_s, vals_s, V);
    transpose_in_kernel<<<4096, 256, 0, stream>>>(x_in, P0, V);

    // ---- helpers ----
    const int SG = (V + 3) / 4;
    auto spmm = [&](const __half* src, __half* dst, const __half* prev, int C) {
        if (C == 16)
            spmm2_kernel<1><<<SG, 256, 0, stream>>>(row_ptr, cols_s, vals_s,
                (const __half2*)src, (__half2*)dst, (const __half2*)prev, V);
        else if (C == 32)
            spmm2_kernel<2><<<SG, 256, 0, stream>>>(row_ptr, cols_s, vals_s,
                (const __half2*)src, (__half2*)dst, (const __half2*)prev, V);
        else
            spmm2_kernel<4><<<SG, 256, 0, stream>>>(row_ptr, cols_s, vals_s,
                (const __half2*)src, (__half2*)dst, (const __half2*)prev, V);
    };
    auto cheb3 = [&](const __half* a, __half* b, __half* c, __half* d, int C) {
        spmm(a, b, nullptr, C);
        spmm(b, c, a, C);
        spmm(c, d, b, C);
    };
    const int MG = (V * 8 + 255) / 256;
    auto comb = [&](const __half* T0, const __half* T1, const __half* T2, const __half* T3,
                    int Cin, int Cout, const float* W, const float* bias,
                    const __half* res, const __half* sc, const float* Wsc,
                    __half* out, int relu) {
        if (Cin == 64 && Cout == 64) {
            wprep_kernel<<<(256 * 64 + 255) / 256, 256, 0, stream>>>(W, wbh, wbl, 256);
            if (sc) wprep_kernel<<<(32 * 64 + 255) / 256, 256, 0, stream>>>(Wsc, wsh, wsl, 32);
            combine64_mfma_kernel<<<(V * 8) / 128, 256, 0, stream>>>(
                T0, T1, T2, T3, wbh, wbl, bias, res, sc, wsh, wsl, out, relu, V);
        } else if (Cin == 16 && Cout == 32)
            combine_kernel<16, 32><<<MG, 256, 0, stream>>>(T0, T1, T2, T3, W, bias, res, sc, Wsc, out, relu, V);
        else if (Cin == 32 && Cout == 32)
            combine_kernel<32, 32><<<MG, 256, 0, stream>>>(T0, T1, T2, T3, W, bias, res, sc, Wsc, out, relu, V);
        else if (Cin == 32 && Cout == 64)
            combine_kernel<32, 64><<<MG, 256, 0, stream>>>(T0, T1, T2, T3, W, bias, res, sc, Wsc, out, relu, V);
        else
            combine_kernel<64, 10><<<MG, 256, 0, stream>>>(T0, T1, T2, T3, W, bias, res, sc, Wsc, out, relu, V);
    };
    auto stats = [&](const __half* xb, int C, int relu, int slot, const float* g, const float* be) {
        bn_stats_part_kernel<<<SB, 256, 0, stream>>>((const __half2*)xb, C, relu, part,
                                                     (size_t)V * 4 * C);
        bn_reduce_kernel<<<1, 64, 0, stream>>>(part, SB, g, be, aff + slot * 128, C,
                                               1.f / ((float)V * 8.f));
    };
    auto affine = [&](__half* xb, int C, int relu, int slot) {
        affine_h_kernel<<<2048, 256, 0, stream>>>(xb, aff + slot * 128, C, relu,
                                                  (size_t)V * 4 * C);
    };
    const __half* NH = nullptr;
    const float*  NF = nullptr;

    // ---- conv_in: x=P0 (16ch) -> relu(cheb+b) -> P4 (32ch) ----
    cheb3(P0, P1, P2, P3, 16);
    comb(P0, P1, P2, P3, 16, 32, W_in, b_in, NH, NH, NF, P4, 1);

    // ---- block 1 (X=P4, 32ch, identity shortcut) ----
    stats(P4, 32, 0, 0, g1a, be1a);
    affine(P4, 32, 0, 0);                   // P4 = xn
    cheb3(P4, P0, P1, P2, 32);
    comb(P4, P0, P1, P2, 32, 32, W1a, b1a, NH, NH, NF, P0, 0);   // out_a = P0
    stats(P0, 32, 1, 1, g1b, be1b);
    affine(P0, 32, 1, 1);                   // P0 = y
    cheb3(P0, P1, P2, P3, 32);
    comb(P0, P1, P2, P3, 32, 32, W1b, b1b, P4, NH, NF, P4, 1);   // P4 = block1 out

    // ---- block 2 (X=P4, 32ch -> 64ch, W2s shortcut) ----
    stats(P4, 32, 0, 2, g2a, be2a);
    affine(P4, 32, 0, 2);                   // P4 = xn (32ch)
    cheb3(P4, P0, P1, P2, 32);
    comb(P4, P0, P1, P2, 32, 64, W2a, b2a, NH, NH, NF, P3, 0);   // out_a = P3 (64ch)
    stats(P3, 64, 1, 3, g2b, be2b);
    affine(P3, 64, 1, 3);                   // P3 = y
    cheb3(P3, P0, P1, P2, 64);
    comb(P3, P0, P1, P2, 64, 64, W2b, b2b, NH, P4, W2s, P0, 1);  // P0 = block2 out (MFMA)

    // ---- block 3 (X=P0, 64ch, identity shortcut) ----
    stats(P0, 64, 0, 4, g3a, be3a);
    affine(P0, 64, 0, 4);                   // P0 = xn
    cheb3(P0, P1, P2, P3, 64);
    comb(P0, P1, P2, P3, 64, 64, W3a, b3a, NH, NH, NF, P1, 0);   // out_a = P1 (MFMA)
    stats(P1, 64, 1, 5, g3b, be3b);
    affine(P1, 64, 1, 5);                   // P1 = y
    cheb3(P1, P2, P3, P4, 64);
    comb(P1, P2, P3, P4, 64, 64, W3b, b3b, P0, NH, NF, P1, 1);   // P1 = block3 out (MFMA)

    // ---- head: bn -> relu(cheb 64->10) -> maxpool -> log_softmax ----
    stats(P1, 64, 0, 6, g_o, be_o);
    affine(P1, 64, 0, 6);                   // P1 = bn(x)
    cheb3(P1, P0, P2, P3, 64);
    comb(P1, P0, P2, P3, 64, 10, W_o, b_o, NH, NH, NF, P4, 1);   // P4 = 80-wide logits
    maxpool_h_kernel<<<80 * NS, 256, 0, stream>>>(P4, pooled, V, NS);
    lsm_kernel<<<1, 64, 0, stream>>>(pooled, (float*)d_out);
}

// Round 16
// 4163.174 us; speedup vs baseline: 1.0795x; 1.0195x over previous
//
#include <hip/hip_runtime.h>
#include <hip/hip_bf16.h>
#include <hip/hip_fp16.h>

// packed fp32 pair — __builtin_elementwise_fma ONLY (round-11: asm FMA 2x
// regression; round-12: float4 W loads neutral -> compiler already optimal).
typedef float v2f __attribute__((ext_vector_type(2)));
__device__ __forceinline__ v2f vfma2(v2f a, v2f b, v2f c) {
#if __has_builtin(__builtin_elementwise_fma)
    return __builtin_elementwise_fma(a, b, c);
#else
    v2f d; d.x = fmaf(a.x, b.x, c.x); d.y = fmaf(a.y, b.y, c.y); return d;
#endif
}

// MFMA vector types (ext vectors, NOT HIP structs)
typedef _Float16 half8v __attribute__((ext_vector_type(8)));
typedef float    f32x4  __attribute__((ext_vector_type(4)));

// ===========================================================================
// CSR build (multi-block scan; deterministic via per-row sort)
// ===========================================================================
__global__ void hist_kernel(const int* __restrict__ rows, int* __restrict__ counts, int E) {
    int i = blockIdx.x * blockDim.x + threadIdx.x;
    if (i < E) atomicAdd(&counts[rows[i]], 1);
}

__global__ void chunk_sum_kernel(const int* __restrict__ counts, int* __restrict__ chunk_sums, int V) {
    __shared__ int sh[256];
    int t = threadIdx.x;
    int i = blockIdx.x * 256 + t;
    sh[t] = (i < V) ? counts[i] : 0;
    __syncthreads();
    for (int st = 128; st > 0; st >>= 1) {
        if (t < st) sh[t] += sh[t + st];
        __syncthreads();
    }
    if (t == 0) chunk_sums[blockIdx.x] = sh[0];
}

__global__ void scan_chunks_kernel(int* __restrict__ cs, int n) {
    __shared__ int wsum[4];
    int t = threadIdx.x, lane = t & 63, w = t >> 6;
    int orig = (t < n) ? cs[t] : 0;
    int x = orig;
    #pragma unroll
    for (int d = 1; d < 64; d <<= 1) {
        int y = __shfl_up(x, d);
        if (lane >= d) x += y;
    }
    if (lane == 63) wsum[w] = x;
    __syncthreads();
    int wo = 0;
    for (int j = 0; j < w; ++j) wo += wsum[j];
    if (t < n) cs[t] = wo + x - orig;     // exclusive
}

__global__ void scan_final_kernel(const int* __restrict__ counts, const int* __restrict__ chunk_off,
                                  int* __restrict__ row_ptr, int V) {
    __shared__ int wsum[4];
    int t = threadIdx.x, lane = t & 63, w = t >> 6;
    int i = blockIdx.x * 256 + t;
    int x = (i < V) ? counts[i] : 0;
    #pragma unroll
    for (int d = 1; d < 64; d <<= 1) {
        int y = __shfl_up(x, d);
        if (lane >= d) x += y;
    }
    if (lane == 63) wsum[w] = x;
    __syncthreads();
    int wo = 0;
    for (int j = 0; j < w; ++j) wo += wsum[j];
    if (i < V) row_ptr[i + 1] = chunk_off[blockIdx.x] + wo + x;
    if (i == 0) row_ptr[0] = 0;
}

__global__ void init_cursor_kernel(const int* __restrict__ row_ptr, int* __restrict__ cursor, int V) {
    int i = blockIdx.x * blockDim.x + threadIdx.x;
    if (i < V) cursor[i] = row_ptr[i];
}

__global__ void scatter_kernel(const int* __restrict__ rows, const int* __restrict__ cols,
                               const float* __restrict__ vals, int* __restrict__ cursor,
                               int* __restrict__ cols_s, float* __restrict__ vals_s, int E) {
    int i = blockIdx.x * blockDim.x + threadIdx.x;
    if (i < E) {
        int r = rows[i];
        int p = atomicAdd(&cursor[r], 1);
        cols_s[p] = cols[i];
        vals_s[p] = vals[i];
    }
}

// canonical per-row order: insertion sort by (col, val-bits). Makes CSR
// bitwise-deterministic regardless of scatter's atomic ordering.
__global__ void sort_rows_kernel(const int* __restrict__ row_ptr, int* cols, float* vals, int V) {
    int v = blockIdx.x * blockDim.x + threadIdx.x;
    if (v >= V) return;
    int e0 = row_ptr[v], e1 = row_ptr[v + 1];
    for (int i = e0 + 1; i < e1; ++i) {
        int c = cols[i];
        unsigned xb = __float_as_uint(vals[i]);
        int j = i - 1;
        while (j >= e0) {
            int cj = cols[j];
            unsigned vj = __float_as_uint(vals[j]);
            if (cj > c || (cj == c && vj > xb)) {
                cols[j + 1] = cj; vals[j + 1] = __uint_as_float(vj);
                --j;
            } else break;
        }
        cols[j + 1] = c;
        vals[j + 1] = __uint_as_float(xb);
    }
}

// ===========================================================================
// transpose input (B,16,V) fp32 -> (V, B*16) fp16
// ===========================================================================
__global__ void transpose_in_kernel(const float* __restrict__ x, __half* __restrict__ X, int V) {
    int total = V * 128;
    for (int i = blockIdx.x * blockDim.x + threadIdx.x; i < total; i += gridDim.x * blockDim.x) {
        int v = i >> 7;
        int t = i & 127;          // t = b*16 + c
        X[i] = __float2half(x[t * V + v]);
    }
}

// ===========================================================================
// SpMM (parked: round-10 A/B showed batch-split neutral). One wave per node;
// 8-deep edge unroll.
// ===========================================================================
template <int VPT> struct PackT;
template <> struct PackT<1> { using T = float;  };
template <> struct PackT<2> { using T = float2; };
template <> struct PackT<4> { using T = float4; };

template <int VPT>
__global__ __launch_bounds__(256) void spmm2_kernel(
    const int* __restrict__ row_ptr, const int* __restrict__ cols,
    const float* __restrict__ vals, const __half2* __restrict__ src,
    __half2* dst, const __half2* prev, int V) {
    using T = typename PackT<VPT>::T;
    union U { T raw; __half2 h[VPT]; };
    int lane = threadIdx.x & 63;
    int v = (blockIdx.x << 2) | (threadIdx.x >> 6);
    if (v >= V) return;
    const int W = VPT * 64;
    const size_t row = (size_t)v * W + lane * VPT;

    float pr[2 * VPT];
    bool hasp = (prev != nullptr);
    if (hasp) {
        U pv; pv.raw = *(const T*)(prev + row);
        #pragma unroll
        for (int j = 0; j < VPT; ++j) {
            float2 f = __half22float2(pv.h[j]);
            pr[2 * j] = f.x; pr[2 * j + 1] = f.y;
        }
    }
    float acc[2 * VPT];
    #pragma unroll
    for (int j = 0; j < 2 * VPT; ++j) acc[j] = 0.f;

    int e0 = row_ptr[v], e1 = row_ptr[v + 1];
    int e = e0;
    for (; e + 8 <= e1; e += 8) {
        int   c[8]; float w[8]; U g[8];
        #pragma unroll
        for (int k = 0; k < 8; ++k) { c[k] = cols[e + k]; w[k] = vals[e + k]; }
        #pragma unroll
        for (int k = 0; k < 8; ++k)
            g[k].raw = *(const T*)(src + (size_t)c[k] * W + lane * VPT);
        #pragma unroll
        for (int k = 0; k < 8; ++k) {
            #pragma unroll
            for (int j = 0; j < VPT; ++j) {
                float2 f = __half22float2(g[k].h[j]);
                acc[2*j] += w[k] * f.x; acc[2*j+1] += w[k] * f.y;
            }
        }
    }
    for (; e + 4 <= e1; e += 4) {
        int   c[4]; float w[4]; U g[4];
        #pragma unroll
        for (int k = 0; k < 4; ++k) { c[k] = cols[e + k]; w[k] = vals[e + k]; }
        #pragma unroll
        for (int k = 0; k < 4; ++k)
            g[k].raw = *(const T*)(src + (size_t)c[k] * W + lane * VPT);
        #pragma unroll
        for (int k = 0; k < 4; ++k) {
            #pragma unroll
            for (int j = 0; j < VPT; ++j) {
                float2 f = __half22float2(g[k].h[j]);
                acc[2*j] += w[k] * f.x; acc[2*j+1] += w[k] * f.y;
            }
        }
    }
    for (; e < e1; ++e) {
        int c = cols[e]; float wv = vals[e];
        U g; g.raw = *(const T*)(src + (size_t)c * W + lane * VPT);
        #pragma unroll
        for (int j = 0; j < VPT; ++j) {
            float2 f = __half22float2(g.h[j]);
            acc[2*j] += wv * f.x; acc[2*j+1] += wv * f.y;
        }
    }
    if (hasp) {
        #pragma unroll
        for (int j = 0; j < 2 * VPT; ++j) acc[j] = 2.f * acc[j] - pr[j];
    }
    U o;
    #pragma unroll
    for (int j = 0; j < VPT; ++j) o.h[j] = __floats2half2_rn(acc[2*j], acc[2*j+1]);
    *(T*)(dst + row) = o.raw;
}

// ===========================================================================
// W prep for MFMA combine: W[kt][co] fp32 -> Bh/Bl[co][kt] fp16 two-term
// split. Transposed so B-fragments are contiguous 16B loads.
// ===========================================================================
__global__ void wprep_kernel(const float* __restrict__ W, __half* __restrict__ Bh,
                             __half* __restrict__ Bl, int KT) {
    int i = blockIdx.x * 256 + threadIdx.x;
    if (i >= KT * 64) return;
    int kt = i >> 6, co = i & 63;
    float w = W[(size_t)kt * 64 + co];
    __half h = __float2half_rn(w);
    Bh[(size_t)co * KT + kt] = h;
    Bl[(size_t)co * KT + kt] = __float2half_rn(w - __half2float(h));
}

// head W prep: W[256][10] -> Bh/Bl[16][256], cols 10..15 zero-padded.
__global__ void wprep_head_kernel(const float* __restrict__ W, __half* __restrict__ Bh,
                                  __half* __restrict__ Bl) {
    int i = blockIdx.x * 256 + threadIdx.x;
    if (i >= 256 * 16) return;
    int kt = i >> 4, co = i & 15;
    float w = (co < 10) ? W[(size_t)kt * 10 + co] : 0.f;
    __half h = __float2half_rn(w);
    Bh[(size_t)co * 256 + kt] = h;
    Bl[(size_t)co * 256 + kt] = __float2half_rn(w - __half2float(h));
}

// ===========================================================================
// combine64 via MFMA, v4 (round-16): v3's 32-row/wave B-reuse confirmed
// (238->155us). v4 doubles again: 64 ROWS/WAVE (four 16-row tiles) -> each
// B fragment feeds 8 MFMAs; per-output B traffic and B-load count halved
// vs v3. A loaded in-loop. Per-output-element MFMA chain order unchanged
// (s asc, h then l) -> bitwise identical to r13..r15. 400000%64==0 ->
// waves all-full-or-dead.
// Aliasing: out may alias T1; each wave reads its 64-row range before
// writing it; ranges disjoint across waves.
// ===========================================================================
__global__ __launch_bounds__(256) void combine64_mfma_kernel(
    const __half* T0, const __half* T1, const __half* T2, const __half* T3,
    const __half* __restrict__ Bh, const __half* __restrict__ Bl,
    const float* __restrict__ bias,
    const __half* res, const __half* sc,
    const __half* __restrict__ Bsh, const __half* __restrict__ Bsl,
    __half* out, int relu, int V) {
    int l   = threadIdx.x & 63;
    int wid = threadIdx.x >> 6;
    int row0 = blockIdx.x * 256 + wid * 64;      // wave owns rows [row0, row0+64)
    if (row0 >= V * 8) return;
    int lr = l & 15, lg = l >> 4;

    f32x4 acc[4][4];                             // [row tile][col tile]
    #pragma unroll
    for (int ct = 0; ct < 4; ++ct) {
        float b = bias ? bias[ct * 16 + lr] : 0.f;
        #pragma unroll
        for (int rt = 0; rt < 4; ++rt) acc[rt][ct] = (f32x4){b, b, b, b};
    }

    const __half* Ts[4] = {T0, T1, T2, T3};
    #pragma unroll
    for (int s = 0; s < 8; ++s) {
        const __half* tb = Ts[s >> 1];
        size_t ao = (size_t)(row0 + lr) * 64 + (s & 1) * 32 + lg * 8;
        half8v a0 = *(const half8v*)(tb + ao);
        half8v a1 = *(const half8v*)(tb + ao + 16 * 64);
        half8v a2 = *(const half8v*)(tb + ao + 32 * 64);
        half8v a3 = *(const half8v*)(tb + ao + 48 * 64);
        #pragma unroll
        for (int ct = 0; ct < 4; ++ct) {
            half8v bh = *(const half8v*)(Bh + (size_t)(ct * 16 + lr) * 256 + s * 32 + lg * 8);
            half8v bl = *(const half8v*)(Bl + (size_t)(ct * 16 + lr) * 256 + s * 32 + lg * 8);
            acc[0][ct] = __builtin_amdgcn_mfma_f32_16x16x32_f16(a0, bh, acc[0][ct], 0, 0, 0);
            acc[0][ct] = __builtin_amdgcn_mfma_f32_16x16x32_f16(a0, bl, acc[0][ct], 0, 0, 0);
            acc[1][ct] = __builtin_amdgcn_mfma_f32_16x16x32_f16(a1, bh, acc[1][ct], 0, 0, 0);
            acc[1][ct] = __builtin_amdgcn_mfma_f32_16x16x32_f16(a1, bl, acc[1][ct], 0, 0, 0);
            acc[2][ct] = __builtin_amdgcn_mfma_f32_16x16x32_f16(a2, bh, acc[2][ct], 0, 0, 0);
            acc[2][ct] = __builtin_amdgcn_mfma_f32_16x16x32_f16(a2, bl, acc[2][ct], 0, 0, 0);
            acc[3][ct] = __builtin_amdgcn_mfma_f32_16x16x32_f16(a3, bh, acc[3][ct], 0, 0, 0);
            acc[3][ct] = __builtin_amdgcn_mfma_f32_16x16x32_f16(a3, bl, acc[3][ct], 0, 0, 0);
        }
    }
    if (sc) {                                   // 32-ch shortcut, single K-slice
        size_t so = (size_t)(row0 + lr) * 32 + lg * 8;
        half8v c0 = *(const half8v*)(sc + so);
        half8v c1 = *(const half8v*)(sc + so + 16 * 32);
        half8v c2 = *(const half8v*)(sc + so + 32 * 32);
        half8v c3 = *(const half8v*)(sc + so + 48 * 32);
        #pragma unroll
        for (int ct = 0; ct < 4; ++ct) {
            half8v bh = *(const half8v*)(Bsh + (size_t)(ct * 16 + lr) * 32 + lg * 8);
            half8v bl = *(const half8v*)(Bsl + (size_t)(ct * 16 + lr) * 32 + lg * 8);
            acc[0][ct] = __builtin_amdgcn_mfma_f32_16x16x32_f16(c0, bh, acc[0][ct], 0, 0, 0);
            acc[0][ct] = __builtin_amdgcn_mfma_f32_16x16x32_f16(c0, bl, acc[0][ct], 0, 0, 0);
            acc[1][ct] = __builtin_amdgcn_mfma_f32_16x16x32_f16(c1, bh, acc[1][ct], 0, 0, 0);
            acc[1][ct] = __builtin_amdgcn_mfma_f32_16x16x32_f16(c1, bl, acc[1][ct], 0, 0, 0);
            acc[2][ct] = __builtin_amdgcn_mfma_f32_16x16x32_f16(c2, bh, acc[2][ct], 0, 0, 0);
            acc[2][ct] = __builtin_amdgcn_mfma_f32_16x16x32_f16(c2, bl, acc[2][ct], 0, 0, 0);
            acc[3][ct] = __builtin_amdgcn_mfma_f32_16x16x32_f16(c3, bh, acc[3][ct], 0, 0, 0);
            acc[3][ct] = __builtin_amdgcn_mfma_f32_16x16x32_f16(c3, bl, acc[3][ct], 0, 0, 0);
        }
    }

    #pragma unroll
    for (int rt = 0; rt < 4; ++rt) {
        #pragma unroll
        for (int ct = 0; ct < 4; ++ct) {
            #pragma unroll
            for (int j = 0; j < 4; ++j) {
                int r = row0 + rt * 16 + lg * 4 + j;
                int c = ct * 16 + lr;
                float v = acc[rt][ct][j];
                if (res) v += __half2float(res[(size_t)r * 64 + c]);
                if (relu) v = fmaxf(v, 0.f);
                out[(size_t)r * 64 + c] = __float2half_rn(v);
            }
        }
    }
}

// ===========================================================================
// head combine <64,10> via MFMA (round-16): v3 structure (32 rows/wave),
// ONE 16-col tile (W zero-padded 10->16 by wprep_head). Padded cols compute
// bias-0 garbage, never written (lr<10 guard). fp16 two-term W split ->
// accuracy >= scalar path. out layout [r][10] (r = v*8+b).
// ===========================================================================
__global__ __launch_bounds__(256) void combine_head_mfma_kernel(
    const __half* T0, const __half* T1, const __half* T2, const __half* T3,
    const __half* __restrict__ Bh, const __half* __restrict__ Bl,
    const float* __restrict__ bias, __half* out, int V) {
    int l   = threadIdx.x & 63;
    int wid = threadIdx.x >> 6;
    int row0 = blockIdx.x * 128 + wid * 32;
    if (row0 >= V * 8) return;
    int lr = l & 15, lg = l >> 4;

    float b = (lr < 10 && bias) ? bias[lr] : 0.f;
    f32x4 acc0 = (f32x4){b, b, b, b};
    f32x4 acc1 = (f32x4){b, b, b, b};

    const __half* Ts[4] = {T0, T1, T2, T3};
    #pragma unroll
    for (int s = 0; s < 8; ++s) {
        const __half* tb = Ts[s >> 1];
        size_t ao = (size_t)(row0 + lr) * 64 + (s & 1) * 32 + lg * 8;
        half8v a0 = *(const half8v*)(tb + ao);
        half8v a1 = *(const half8v*)(tb + ao + 16 * 64);
        half8v bh = *(const half8v*)(Bh + (size_t)lr * 256 + s * 32 + lg * 8);
        half8v bl = *(const half8v*)(Bl + (size_t)lr * 256 + s * 32 + lg * 8);
        acc0 = __builtin_amdgcn_mfma_f32_16x16x32_f16(a0, bh, acc0, 0, 0, 0);
        acc0 = __builtin_amdgcn_mfma_f32_16x16x32_f16(a0, bl, acc0, 0, 0, 0);
        acc1 = __builtin_amdgcn_mfma_f32_16x16x32_f16(a1, bh, acc1, 0, 0, 0);
        acc1 = __builtin_amdgcn_mfma_f32_16x16x32_f16(a1, bl, acc1, 0, 0, 0);
    }

    if (lr < 10) {
        #pragma unroll
        for (int rt = 0; rt < 2; ++rt) {
            f32x4 acc = rt ? acc1 : acc0;
            #pragma unroll
            for (int j = 0; j < 4; ++j) {
                int r = row0 + rt * 16 + lg * 4 + j;
                float v = fmaxf(acc[j], 0.f);               // head relu
                out[(size_t)r * 10 + lr] = __float2half_rn(v);
            }
        }
    }
}

// ===========================================================================
// combine v11 (scalar path, kept for 16x32 / 32x32 / 32x64 shapes)
// ===========================================================================
template <int CIN, int COUT>
__global__ __launch_bounds__(256) void combine_kernel(
    const __half* T0, const __half* T1, const __half* T2, const __half* T3,
    const float* __restrict__ W, const float* __restrict__ bias,
    const __half* res, const __half* sc, const float* __restrict__ Wsc,
    __half* out, int relu, int V) {
    constexpr int SL    = CIN / 8;               // float4 slots per row
    constexpr int BURST = (SL < 4) ? SL : 4;     // 4 float4 = one 64B sector
    constexpr int NB    = SL / BURST;
    constexpr int SLS   = 32 / 8;                // shortcut always 32ch
    union U4 { float4 raw; __half2 h[4]; };
    union UW { float4 raw; v2f p[2]; };

    int g = blockIdx.x * 256 + threadIdx.x;
    if (g >= V * 8) return;

    v2f acc[COUT / 2];
    #pragma unroll
    for (int c = 0; c < COUT / 2; ++c) {
        if (bias) { acc[c].x = bias[2 * c]; acc[c].y = bias[2 * c + 1]; }
        else      { acc[c].x = 0.f;         acc[c].y = 0.f; }
    }

    auto rank1 = [&](float2 a, const float* w0f, const float* w1f) {
        v2f ax = {a.x, a.x}, ay = {a.y, a.y};
        if constexpr (COUT % 4 == 0) {
            const float4* w0 = (const float4*)w0f;
            const float4* w1 = (const float4*)w1f;
            #pragma unroll
            for (int cw = 0; cw < COUT / 4; ++cw) {
                UW A; A.raw = w0[cw];
                UW B; B.raw = w1[cw];
                acc[2 * cw]     = vfma2(ax, A.p[0], acc[2 * cw]);
                acc[2 * cw]     = vfma2(ay, B.p[0], acc[2 * cw]);
                acc[2 * cw + 1] = vfma2(ax, A.p[1], acc[2 * cw + 1]);
                acc[2 * cw + 1] = vfma2(ay, B.p[1], acc[2 * cw + 1]);
            }
        } else {
            const v2f* w0 = (const v2f*)w0f;
            const v2f* w1 = (const v2f*)w1f;
            #pragma unroll
            for (int c = 0; c < COUT / 2; ++c) {
                acc[c] = vfma2(ax, w0[c], acc[c]);
                acc[c] = vfma2(ay, w1[c], acc[c]);
            }
        }
    };

    const __half* Ts[4] = {T0, T1, T2, T3};
    #pragma unroll 1
    for (int k = 0; k < 4; ++k) {
        const float4* rp = (const float4*)(Ts[k] + (size_t)g * CIN);
        const float* Wk = W + (size_t)k * CIN * COUT;
        #pragma unroll 1
        for (int b2 = 0; b2 < NB; ++b2) {
            U4 x[BURST];
            #pragma unroll
            for (int j = 0; j < BURST; ++j) x[j].raw = rp[b2 * BURST + j];
            #pragma unroll
            for (int j = 0; j < BURST; ++j) {
                #pragma unroll
                for (int s = 0; s < 4; ++s) {
                    int q = (b2 * BURST + j) * 4 + s;
                    float2 a = __half22float2(x[j].h[s]);
                    rank1(a, Wk + (size_t)(2 * q) * COUT,
                             Wk + (size_t)(2 * q + 1) * COUT);
                }
            }
        }
    }
    if (sc) {
        const float4* sp = (const float4*)(sc + (size_t)g * 32);
        U4 x[SLS];
        #pragma unroll
        for (int j = 0; j < SLS; ++j) x[j].raw = sp[j];
        #pragma unroll
        for (int j = 0; j < SLS; ++j) {
            #pragma unroll
            for (int s = 0; s < 4; ++s) {
                int q = j * 4 + s;
                float2 a = __half22float2(x[j].h[s]);
                rank1(a, Wsc + (size_t)(2 * q) * COUT,
                         Wsc + (size_t)(2 * q + 1) * COUT);
            }
        }
    }

    size_t ob = (size_t)g * COUT;
    if constexpr (COUT % 8 == 0) {
        if (res) {
            const float4* rr = (const float4*)(res + ob);
            #pragma unroll
            for (int q = 0; q < COUT / 8; ++q) {
                U4 rv; rv.raw = rr[q];
                #pragma unroll
                for (int s = 0; s < 4; ++s) {
                    float2 f = __half22float2(rv.h[s]);
                    acc[q * 4 + s].x += f.x; acc[q * 4 + s].y += f.y;
                }
            }
        }
        if (relu) {
            #pragma unroll
            for (int c = 0; c < COUT / 2; ++c) {
                acc[c].x = fmaxf(acc[c].x, 0.f);
                acc[c].y = fmaxf(acc[c].y, 0.f);
            }
        }
        float4* ro = (float4*)(out + ob);
        #pragma unroll
        for (int q = 0; q < COUT / 8; ++q) {
            U4 o;
            #pragma unroll
            for (int s = 0; s < 4; ++s)
                o.h[s] = __floats2half2_rn(acc[q * 4 + s].x, acc[q * 4 + s].y);
            ro[q] = o.raw;
        }
    } else {
        if (res) {
            const __half2* rr = (const __half2*)(res + ob);
            #pragma unroll
            for (int c = 0; c < COUT / 2; ++c) {
                float2 f = __half22float2(rr[c]);
                acc[c].x += f.x; acc[c].y += f.y;
            }
        }
        if (relu) {
            #pragma unroll
            for (int c = 0; c < COUT / 2; ++c) {
                acc[c].x = fmaxf(acc[c].x, 0.f);
                acc[c].y = fmaxf(acc[c].y, 0.f);
            }
        }
        __half2* ro = (__half2*)(out + ob);
        #pragma unroll
        for (int c = 0; c < COUT / 2; ++c)
            ro[c] = __floats2half2_rn(acc[c].x, acc[c].y);
    }
}

// ===========================================================================
// BatchNorm: two-stage deterministic stats (no float atomics), SB=512.
// ===========================================================================
__global__ void bn_stats_part_kernel(const __half2* __restrict__ x2, int C, int relu_in,
                                     float* __restrict__ part, size_t N2) {
    __shared__ float sx[256], qx[256], sy[256], qy[256];
    int t = threadIdx.x;
    size_t i0 = (size_t)blockIdx.x * 256 + t;
    size_t step = (size_t)gridDim.x * 256;
    float ax = 0.f, aqx = 0.f, ay = 0.f, aqy = 0.f;
    for (size_t i = i0; i < N2; i += step) {
        float2 f = __half22float2(x2[i]);
        if (relu_in) { f.x = fmaxf(f.x, 0.f); f.y = fmaxf(f.y, 0.f); }
        ax += f.x; aqx += f.x * f.x;
        ay += f.y; aqy += f.y * f.y;
    }
    sx[t] = ax; qx[t] = aqx; sy[t] = ay; qy[t] = aqy;
    __syncthreads();
    int half = C >> 1;
    for (int st = 128; st >= half; st >>= 1) {
        if (t < st) {
            sx[t] += sx[t + st]; qx[t] += qx[t + st];
            sy[t] += sy[t + st]; qy[t] += qy[t + st];
        }
        __syncthreads();
    }
    if (t < half) {
        part[blockIdx.x * 128 + 2 * t]         = sx[t];
        part[blockIdx.x * 128 + 2 * t + 1]     = sy[t];
        part[blockIdx.x * 128 + C + 2 * t]     = qx[t];
        part[blockIdx.x * 128 + C + 2 * t + 1] = qy[t];
    }
}

__global__ void bn_reduce_kernel(const float* __restrict__ part, int nblk,
                                 const float* __restrict__ g, const float* __restrict__ be,
                                 float* __restrict__ ss, int C, float invN) {
    int c = threadIdx.x;
    if (c < C) {
        float s = 0.f, q = 0.f;
        for (int b = 0; b < nblk; ++b) {        // fixed order -> deterministic
            s += part[b * 128 + c];
            q += part[b * 128 + C + c];
        }
        float m = s * invN;
        float var = q * invN - m * m;
        float sc = g[c] * rsqrtf(var + 1e-5f);
        ss[c] = sc;
        ss[C + c] = be[c] - m * sc;
    }
}

// in-place: x = f(x)*a + b, f = relu if relu_in. float4-vectorized.
__global__ void affine_h_kernel(__half* x, const float* __restrict__ ss, int C,
                                int relu_in, size_t N2) {
    union U4 { float4 raw; __half2 h[4]; };
    size_t NG = N2 >> 2;
    size_t stride = (size_t)gridDim.x * blockDim.x;
    size_t i0 = (size_t)blockIdx.x * blockDim.x + threadIdx.x;
    float4* x4 = (float4*)x;
    int c0 = (int)((8 * i0) & (size_t)(C - 1));
    float sc[8], of[8];
    #pragma unroll
    for (int j = 0; j < 8; ++j) { sc[j] = ss[c0 + j]; of[j] = ss[C + c0 + j]; }
    for (size_t i = i0; i < NG; i += stride) {
        U4 u; u.raw = x4[i];
        #pragma unroll
        for (int j = 0; j < 4; ++j) {
            float2 f = __half22float2(u.h[j]);
            if (relu_in) { f.x = fmaxf(f.x, 0.f); f.y = fmaxf(f.y, 0.f); }
            f.x = f.x * sc[2 * j] + of[2 * j];
            f.y = f.y * sc[2 * j + 1] + of[2 * j + 1];
            u.h[j] = __floats2half2_rn(f.x, f.y);
        }
        x4[i] = u.raw;
    }
}

// ===========================================================================
// head: partial max + int-atomicMax, then log_softmax
// ===========================================================================
__global__ void maxpool_h_kernel(const __half* __restrict__ x, float* pooled, int V, int NS) {
    __shared__ float red[256];
    int o = blockIdx.x % 80;
    int slice = blockIdx.x / 80;
    int v0 = (int)((long long)V * slice / NS);
    int v1 = (int)((long long)V * (slice + 1) / NS);
    float m = 0.f;
    for (int v = v0 + threadIdx.x; v < v1; v += 256)
        m = fmaxf(m, __half2float(x[(size_t)v * 80 + o]));
    red[threadIdx.x] = m;
    __syncthreads();
    for (int st = 128; st > 0; st >>= 1) {
        if (threadIdx.x < st) red[threadIdx.x] = fmaxf(red[threadIdx.x], red[threadIdx.x + st]);
        __syncthreads();
    }
    if (threadIdx.x == 0) atomicMax((int*)&pooled[o], __float_as_int(red[0]));
}

__global__ void lsm_kernel(const float* __restrict__ pooled, float* __restrict__ out) {
    int b = threadIdx.x;
    if (b < 8) {
        float m = -1e30f;
        for (int c = 0; c < 10; ++c) m = fmaxf(m, pooled[b * 10 + c]);
        float s = 0.f;
        for (int c = 0; c < 10; ++c) s += expf(pooled[b * 10 + c] - m);
        float l = logf(s);
        for (int c = 0; c < 10; ++c)
            out[b * 10 + c] = pooled[b * 10 + c] - m - l;
    }
}

__global__ void encode_kernel(float* out, float val) {
    int i = threadIdx.x;
    if (i < 80) out[i] = val;
}

// ===========================================================================
// entry
// ===========================================================================
extern "C" void kernel_launch(void* const* d_in, const int* in_sizes, int n_in,
                              void* d_out, int out_size, void* d_ws, size_t ws_size,
                              hipStream_t stream) {
    (void)in_sizes; (void)n_in; (void)out_size;
    const int V = 50000, E = 800000;
    const int NCH = (V + 255) / 256;
    const int SB = 512;                       // bn stage-1 blocks
    const int NS = 8;                         // maxpool node slices

    auto al = [](size_t x) { return (x + 255) & ~(size_t)255; };
    const size_t FB = al((size_t)V * 512 * sizeof(__half));     // 51.2 MB
    const size_t WPB = al((size_t)256 * 64 * 2) * 2 + al((size_t)32 * 64 * 2) * 2
                     + al((size_t)256 * 16 * 2) * 2;
    const size_t need = 5 * FB + al((V + 1) * 4) + al(V * 4) + al(E * 4) + al(E * 4)
                      + al((size_t)SB * 128 * 4) + al(8 * 128 * 4) + al(80 * 4) + al(NCH * 4)
                      + WPB;
    if (ws_size < need) {
        encode_kernel<<<1, 128, 0, stream>>>((float*)d_out, (float)(ws_size >> 20));
        return;
    }

    const float* x_in = (const float*)d_in[0];
    const int* rows   = (const int*)d_in[1];
    const int* colsi  = (const int*)d_in[2];
    const float* lvals = (const float*)d_in[3];
    const float* W_in = (const float*)d_in[4];
    const float* b_in = (const float*)d_in[5];
    const float* g1a = (const float*)d_in[6],  *be1a = (const float*)d_in[7];
    const float* W1a = (const float*)d_in[8],  *b1a  = (const float*)d_in[9];
    const float* g1b = (const float*)d_in[10], *be1b = (const float*)d_in[11];
    const float* W1b = (const float*)d_in[12], *b1b  = (const float*)d_in[13];
    const float* g2a = (const float*)d_in[14], *be2a = (const float*)d_in[15];
    const float* W2a = (const float*)d_in[16], *b2a  = (const float*)d_in[17];
    const float* g2b = (const float*)d_in[18], *be2b = (const float*)d_in[19];
    const float* W2b = (const float*)d_in[20], *b2b  = (const float*)d_in[21];
    const float* W2s = (const float*)d_in[22];
    const float* g3a = (const float*)d_in[23], *be3a = (const float*)d_in[24];
    const float* W3a = (const float*)d_in[25], *b3a  = (const float*)d_in[26];
    const float* g3b = (const float*)d_in[27], *be3b = (const float*)d_in[28];
    const float* W3b = (const float*)d_in[29], *b3b  = (const float*)d_in[30];
    const float* g_o = (const float*)d_in[31], *be_o = (const float*)d_in[32];
    const float* W_o = (const float*)d_in[33], *b_o  = (const float*)d_in[34];

    char* wp = (char*)d_ws;
    auto take = [&](size_t bytes) -> void* { void* p = (void*)wp; wp += al(bytes); return p; };
    __half* P0 = (__half*)take(FB);
    __half* P1 = (__half*)take(FB);
    __half* P2 = (__half*)take(FB);
    __half* P3 = (__half*)take(FB);
    __half* P4 = (__half*)take(FB);
    int* row_ptr  = (int*)take((V + 1) * sizeof(int));
    int* cursor   = (int*)take(V * sizeof(int));
    int* cols_s   = (int*)take(E * sizeof(int));
    float* vals_s = (float*)take(E * sizeof(float));
    float* part   = (float*)take((size_t)SB * 128 * sizeof(float));
    float* aff    = (float*)take(8 * 128 * sizeof(float));
    float* pooled = (float*)take(80 * sizeof(float));
    int* chunks   = (int*)take(NCH * sizeof(int));
    __half* wbh   = (__half*)take((size_t)256 * 64 * 2);
    __half* wbl   = (__half*)take((size_t)256 * 64 * 2);
    __half* wsh   = (__half*)take((size_t)32 * 64 * 2);
    __half* wsl   = (__half*)take((size_t)32 * 64 * 2);
    __half* whh   = (__half*)take((size_t)256 * 16 * 2);
    __half* whl   = (__half*)take((size_t)256 * 16 * 2);

    hipMemsetAsync(cursor, 0, V * sizeof(int), stream);
    hipMemsetAsync(pooled, 0, 80 * sizeof(float), stream);

    // ---- CSR build (+canonical row order) + input transpose ----
    hist_kernel<<<(E + 255) / 256, 256, 0, stream>>>(rows, cursor, E);
    chunk_sum_kernel<<<NCH, 256, 0, stream>>>(cursor, chunks, V);
    scan_chunks_kernel<<<1, 256, 0, stream>>>(chunks, NCH);
    scan_final_kernel<<<NCH, 256, 0, stream>>>(cursor, chunks, row_ptr, V);
    init_cursor_kernel<<<(V + 255) / 256, 256, 0, stream>>>(row_ptr, cursor, V);
    scatter_kernel<<<(E + 255) / 256, 256, 0, stream>>>(rows, colsi, lvals, cursor, cols_s, vals_s, E);
    sort_rows_kernel<<<(V + 255) / 256, 256, 0, stream>>>(row_ptr, cols_s, vals_s, V);
    transpose_in_kernel<<<4096, 256, 0, stream>>>(x_in, P0, V);

    // ---- helpers ----
    const int SG = (V + 3) / 4;
    auto spmm = [&](const __half* src, __half* dst, const __half* prev, int C) {
        if (C == 16)
            spmm2_kernel<1><<<SG, 256, 0, stream>>>(row_ptr, cols_s, vals_s,
                (const __half2*)src, (__half2*)dst, (const __half2*)prev, V);
        else if (C == 32)
            spmm2_kernel<2><<<SG, 256, 0, stream>>>(row_ptr, cols_s, vals_s,
                (const __half2*)src, (__half2*)dst, (const __half2*)prev, V);
        else
            spmm2_kernel<4><<<SG, 256, 0, stream>>>(row_ptr, cols_s, vals_s,
                (const __half2*)src, (__half2*)dst, (const __half2*)prev, V);
    };
    auto cheb3 = [&](const __half* a, __half* b, __half* c, __half* d, int C) {
        spmm(a, b, nullptr, C);
        spmm(b, c, a, C);
        spmm(c, d, b, C);
    };
    const int MG = (V * 8 + 255) / 256;
    auto comb = [&](const __half* T0, const __half* T1, const __half* T2, const __half* T3,
                    int Cin, int Cout, const float* W, const float* bias,
                    const __half* res, const __half* sc, const float* Wsc,
                    __half* out, int relu) {
        if (Cin == 64 && Cout == 64) {
            wprep_kernel<<<(256 * 64 + 255) / 256, 256, 0, stream>>>(W, wbh, wbl, 256);
            if (sc) wprep_kernel<<<(32 * 64 + 255) / 256, 256, 0, stream>>>(Wsc, wsh, wsl, 32);
            combine64_mfma_kernel<<<(V * 8 + 255) / 256, 256, 0, stream>>>(
                T0, T1, T2, T3, wbh, wbl, bias, res, sc, wsh, wsl, out, relu, V);
        } else if (Cin == 64 && Cout == 10) {
            wprep_head_kernel<<<(256 * 16 + 255) / 256, 256, 0, stream>>>(W, whh, whl);
            combine_head_mfma_kernel<<<(V * 8 + 127) / 128, 256, 0, stream>>>(
                T0, T1, T2, T3, whh, whl, bias, out, V);
        } else if (Cin == 16 && Cout == 32)
            combine_kernel<16, 32><<<MG, 256, 0, stream>>>(T0, T1, T2, T3, W, bias, res, sc, Wsc, out, relu, V);
        else if (Cin == 32 && Cout == 32)
            combine_kernel<32, 32><<<MG, 256, 0, stream>>>(T0, T1, T2, T3, W, bias, res, sc, Wsc, out, relu, V);
        else
            combine_kernel<32, 64><<<MG, 256, 0, stream>>>(T0, T1, T2, T3, W, bias, res, sc, Wsc, out, relu, V);
    };
    auto stats = [&](const __half* xb, int C, int relu, int slot, const float* g, const float* be) {
        bn_stats_part_kernel<<<SB, 256, 0, stream>>>((const __half2*)xb, C, relu, part,
                                                     (size_t)V * 4 * C);
        bn_reduce_kernel<<<1, 64, 0, stream>>>(part, SB, g, be, aff + slot * 128, C,
                                               1.f / ((float)V * 8.f));
    };
    auto affine = [&](__half* xb, int C, int relu, int slot) {
        affine_h_kernel<<<2048, 256, 0, stream>>>(xb, aff + slot * 128, C, relu,
                                                  (size_t)V * 4 * C);
    };
    const __half* NH = nullptr;
    const float*  NF = nullptr;

    // ---- conv_in: x=P0 (16ch) -> relu(cheb+b) -> P4 (32ch) ----
    cheb3(P0, P1, P2, P3, 16);
    comb(P0, P1, P2, P3, 16, 32, W_in, b_in, NH, NH, NF, P4, 1);

    // ---- block 1 (X=P4, 32ch, identity shortcut) ----
    stats(P4, 32, 0, 0, g1a, be1a);
    affine(P4, 32, 0, 0);                   // P4 = xn
    cheb3(P4, P0, P1, P2, 32);
    comb(P4, P0, P1, P2, 32, 32, W1a, b1a, NH, NH, NF, P0, 0);   // out_a = P0
    stats(P0, 32, 1, 1, g1b, be1b);
    affine(P0, 32, 1, 1);                   // P0 = y
    cheb3(P0, P1, P2, P3, 32);
    comb(P0, P1, P2, P3, 32, 32, W1b, b1b, P4, NH, NF, P4, 1);   // P4 = block1 out

    // ---- block 2 (X=P4, 32ch -> 64ch, W2s shortcut) ----
    stats(P4, 32, 0, 2, g2a, be2a);
    affine(P4, 32, 0, 2);                   // P4 = xn (32ch)
    cheb3(P4, P0, P1, P2, 32);
    comb(P4, P0, P1, P2, 32, 64, W2a, b2a, NH, NH, NF, P3, 0);   // out_a = P3 (64ch)
    stats(P3, 64, 1, 3, g2b, be2b);
    affine(P3, 64, 1, 3);                   // P3 = y
    cheb3(P3, P0, P1, P2, 64);
    comb(P3, P0, P1, P2, 64, 64, W2b, b2b, NH, P4, W2s, P0, 1);  // P0 = block2 out (MFMA)

    // ---- block 3 (X=P0, 64ch, identity shortcut) ----
    stats(P0, 64, 0, 4, g3a, be3a);
    affine(P0, 64, 0, 4);                   // P0 = xn
    cheb3(P0, P1, P2, P3, 64);
    comb(P0, P1, P2, P3, 64, 64, W3a, b3a, NH, NH, NF, P1, 0);   // out_a = P1 (MFMA)
    stats(P1, 64, 1, 5, g3b, be3b);
    affine(P1, 64, 1, 5);                   // P1 = y
    cheb3(P1, P2, P3, P4, 64);
    comb(P1, P2, P3, P4, 64, 64, W3b, b3b, P0, NH, NF, P1, 1);   // P1 = block3 out (MFMA)

    // ---- head: bn -> relu(cheb 64->10) -> maxpool -> log_softmax ----
    stats(P1, 64, 0, 6, g_o, be_o);
    affine(P1, 64, 0, 6);                   // P1 = bn(x)
    cheb3(P1, P0, P2, P3, 64);
    comb(P1, P0, P2, P3, 64, 10, W_o, b_o, NH, NH, NF, P4, 1);   // P4 logits (MFMA head)
    maxpool_h_kernel<<<80 * NS, 256, 0, stream>>>(P4, pooled, V, NS);
    lsm_kernel<<<1, 64, 0, stream>>>(pooled, (float*)d_out);
}

// Round 17
// 4067.044 us; speedup vs baseline: 1.1050x; 1.0236x over previous
//
#include <hip/hip_runtime.h>
#include <hip/hip_bf16.h>
#include <hip/hip_fp16.h>

// packed fp32 pair — __builtin_elementwise_fma ONLY (round-11: asm FMA 2x
// regression; round-12: float4 W loads neutral -> compiler already optimal).
typedef float v2f __attribute__((ext_vector_type(2)));
__device__ __forceinline__ v2f vfma2(v2f a, v2f b, v2f c) {
#if __has_builtin(__builtin_elementwise_fma)
    return __builtin_elementwise_fma(a, b, c);
#else
    v2f d; d.x = fmaf(a.x, b.x, c.x); d.y = fmaf(a.y, b.y, c.y); return d;
#endif
}

// MFMA vector types (ext vectors, NOT HIP structs)
typedef _Float16 half8v __attribute__((ext_vector_type(8)));
typedef float    f32x4  __attribute__((ext_vector_type(4)));

// ===========================================================================
// CSR build (multi-block scan; deterministic via per-row sort)
// ===========================================================================
__global__ void hist_kernel(const int* __restrict__ rows, int* __restrict__ counts, int E) {
    int i = blockIdx.x * blockDim.x + threadIdx.x;
    if (i < E) atomicAdd(&counts[rows[i]], 1);
}

__global__ void chunk_sum_kernel(const int* __restrict__ counts, int* __restrict__ chunk_sums, int V) {
    __shared__ int sh[256];
    int t = threadIdx.x;
    int i = blockIdx.x * 256 + t;
    sh[t] = (i < V) ? counts[i] : 0;
    __syncthreads();
    for (int st = 128; st > 0; st >>= 1) {
        if (t < st) sh[t] += sh[t + st];
        __syncthreads();
    }
    if (t == 0) chunk_sums[blockIdx.x] = sh[0];
}

__global__ void scan_chunks_kernel(int* __restrict__ cs, int n) {
    __shared__ int wsum[4];
    int t = threadIdx.x, lane = t & 63, w = t >> 6;
    int orig = (t < n) ? cs[t] : 0;
    int x = orig;
    #pragma unroll
    for (int d = 1; d < 64; d <<= 1) {
        int y = __shfl_up(x, d);
        if (lane >= d) x += y;
    }
    if (lane == 63) wsum[w] = x;
    __syncthreads();
    int wo = 0;
    for (int j = 0; j < w; ++j) wo += wsum[j];
    if (t < n) cs[t] = wo + x - orig;     // exclusive
}

__global__ void scan_final_kernel(const int* __restrict__ counts, const int* __restrict__ chunk_off,
                                  int* __restrict__ row_ptr, int V) {
    __shared__ int wsum[4];
    int t = threadIdx.x, lane = t & 63, w = t >> 6;
    int i = blockIdx.x * 256 + t;
    int x = (i < V) ? counts[i] : 0;
    #pragma unroll
    for (int d = 1; d < 64; d <<= 1) {
        int y = __shfl_up(x, d);
        if (lane >= d) x += y;
    }
    if (lane == 63) wsum[w] = x;
    __syncthreads();
    int wo = 0;
    for (int j = 0; j < w; ++j) wo += wsum[j];
    if (i < V) row_ptr[i + 1] = chunk_off[blockIdx.x] + wo + x;
    if (i == 0) row_ptr[0] = 0;
}

__global__ void init_cursor_kernel(const int* __restrict__ row_ptr, int* __restrict__ cursor, int V) {
    int i = blockIdx.x * blockDim.x + threadIdx.x;
    if (i < V) cursor[i] = row_ptr[i];
}

__global__ void scatter_kernel(const int* __restrict__ rows, const int* __restrict__ cols,
                               const float* __restrict__ vals, int* __restrict__ cursor,
                               int* __restrict__ cols_s, float* __restrict__ vals_s, int E) {
    int i = blockIdx.x * blockDim.x + threadIdx.x;
    if (i < E) {
        int r = rows[i];
        int p = atomicAdd(&cursor[r], 1);
        cols_s[p] = cols[i];
        vals_s[p] = vals[i];
    }
}

// canonical per-row order: insertion sort by (col, val-bits). Makes CSR
// bitwise-deterministic regardless of scatter's atomic ordering.
__global__ void sort_rows_kernel(const int* __restrict__ row_ptr, int* cols, float* vals, int V) {
    int v = blockIdx.x * blockDim.x + threadIdx.x;
    if (v >= V) return;
    int e0 = row_ptr[v], e1 = row_ptr[v + 1];
    for (int i = e0 + 1; i < e1; ++i) {
        int c = cols[i];
        unsigned xb = __float_as_uint(vals[i]);
        int j = i - 1;
        while (j >= e0) {
            int cj = cols[j];
            unsigned vj = __float_as_uint(vals[j]);
            if (cj > c || (cj == c && vj > xb)) {
                cols[j + 1] = cj; vals[j + 1] = __uint_as_float(vj);
                --j;
            } else break;
        }
        cols[j + 1] = c;
        vals[j + 1] = __uint_as_float(xb);
    }
}

// ===========================================================================
// transpose input (B,16,V) fp32 -> (V, B*16) fp16
// ===========================================================================
__global__ void transpose_in_kernel(const float* __restrict__ x, __half* __restrict__ X, int V) {
    int total = V * 128;
    for (int i = blockIdx.x * blockDim.x + threadIdx.x; i < total; i += gridDim.x * blockDim.x) {
        int v = i >> 7;
        int t = i & 127;          // t = b*16 + c
        X[i] = __float2half(x[t * V + v]);
    }
}

// ===========================================================================
// SpMM (parked: round-10 A/B showed batch-split neutral). One wave per node;
// 8-deep edge unroll.
// ===========================================================================
template <int VPT> struct PackT;
template <> struct PackT<1> { using T = float;  };
template <> struct PackT<2> { using T = float2; };
template <> struct PackT<4> { using T = float4; };

template <int VPT>
__global__ __launch_bounds__(256) void spmm2_kernel(
    const int* __restrict__ row_ptr, const int* __restrict__ cols,
    const float* __restrict__ vals, const __half2* __restrict__ src,
    __half2* dst, const __half2* prev, int V) {
    using T = typename PackT<VPT>::T;
    union U { T raw; __half2 h[VPT]; };
    int lane = threadIdx.x & 63;
    int v = (blockIdx.x << 2) | (threadIdx.x >> 6);
    if (v >= V) return;
    const int W = VPT * 64;
    const size_t row = (size_t)v * W + lane * VPT;

    float pr[2 * VPT];
    bool hasp = (prev != nullptr);
    if (hasp) {
        U pv; pv.raw = *(const T*)(prev + row);
        #pragma unroll
        for (int j = 0; j < VPT; ++j) {
            float2 f = __half22float2(pv.h[j]);
            pr[2 * j] = f.x; pr[2 * j + 1] = f.y;
        }
    }
    float acc[2 * VPT];
    #pragma unroll
    for (int j = 0; j < 2 * VPT; ++j) acc[j] = 0.f;

    int e0 = row_ptr[v], e1 = row_ptr[v + 1];
    int e = e0;
    for (; e + 8 <= e1; e += 8) {
        int   c[8]; float w[8]; U g[8];
        #pragma unroll
        for (int k = 0; k < 8; ++k) { c[k] = cols[e + k]; w[k] = vals[e + k]; }
        #pragma unroll
        for (int k = 0; k < 8; ++k)
            g[k].raw = *(const T*)(src + (size_t)c[k] * W + lane * VPT);
        #pragma unroll
        for (int k = 0; k < 8; ++k) {
            #pragma unroll
            for (int j = 0; j < VPT; ++j) {
                float2 f = __half22float2(g[k].h[j]);
                acc[2*j] += w[k] * f.x; acc[2*j+1] += w[k] * f.y;
            }
        }
    }
    for (; e + 4 <= e1; e += 4) {
        int   c[4]; float w[4]; U g[4];
        #pragma unroll
        for (int k = 0; k < 4; ++k) { c[k] = cols[e + k]; w[k] = vals[e + k]; }
        #pragma unroll
        for (int k = 0; k < 4; ++k)
            g[k].raw = *(const T*)(src + (size_t)c[k] * W + lane * VPT);
        #pragma unroll
        for (int k = 0; k < 4; ++k) {
            #pragma unroll
            for (int j = 0; j < VPT; ++j) {
                float2 f = __half22float2(g[k].h[j]);
                acc[2*j] += w[k] * f.x; acc[2*j+1] += w[k] * f.y;
            }
        }
    }
    for (; e < e1; ++e) {
        int c = cols[e]; float wv = vals[e];
        U g; g.raw = *(const T*)(src + (size_t)c * W + lane * VPT);
        #pragma unroll
        for (int j = 0; j < VPT; ++j) {
            float2 f = __half22float2(g.h[j]);
            acc[2*j] += wv * f.x; acc[2*j+1] += wv * f.y;
        }
    }
    if (hasp) {
        #pragma unroll
        for (int j = 0; j < 2 * VPT; ++j) acc[j] = 2.f * acc[j] - pr[j];
    }
    U o;
    #pragma unroll
    for (int j = 0; j < VPT; ++j) o.h[j] = __floats2half2_rn(acc[2*j], acc[2*j+1]);
    *(T*)(dst + row) = o.raw;
}

// ===========================================================================
// W prep for MFMA combine: W[kt][co] fp32 -> Bh/Bl[co][kt] fp16 two-term
// split. Transposed so B-fragments are contiguous 16B loads. Generic CO.
// ===========================================================================
__global__ void wprep_kernel(const float* __restrict__ W, __half* __restrict__ Bh,
                             __half* __restrict__ Bl, int KT, int CO) {
    int i = blockIdx.x * 256 + threadIdx.x;
    if (i >= KT * CO) return;
    int kt = i / CO, co = i % CO;
    float w = W[(size_t)kt * CO + co];
    __half h = __float2half_rn(w);
    Bh[(size_t)co * KT + kt] = h;
    Bl[(size_t)co * KT + kt] = __float2half_rn(w - __half2float(h));
}

// head W prep: W[256][10] -> Bh/Bl[16][256], cols 10..15 zero-padded.
__global__ void wprep_head_kernel(const float* __restrict__ W, __half* __restrict__ Bh,
                                  __half* __restrict__ Bl) {
    int i = blockIdx.x * 256 + threadIdx.x;
    if (i >= 256 * 16) return;
    int kt = i >> 4, co = i & 15;
    float w = (co < 10) ? W[(size_t)kt * 10 + co] : 0.f;
    __half h = __float2half_rn(w);
    Bh[(size_t)co * 256 + kt] = h;
    Bl[(size_t)co * 256 + kt] = __float2half_rn(w - __half2float(h));
}

// ===========================================================================
// combine64 via MFMA, v4 (proven r16: 135us): 64 rows/wave, 4x4 tile grid,
// fp16 two-term W split, fp32 acc. MFMA order: s asc, h then l -> bitwise
// deterministic. Aliasing: out may alias T1; wave reads its 64-row range
// (every slice) before writing it; ranges disjoint.
// ===========================================================================
__global__ __launch_bounds__(256) void combine64_mfma_kernel(
    const __half* T0, const __half* T1, const __half* T2, const __half* T3,
    const __half* __restrict__ Bh, const __half* __restrict__ Bl,
    const float* __restrict__ bias,
    const __half* res, const __half* sc,
    const __half* __restrict__ Bsh, const __half* __restrict__ Bsl,
    __half* out, int relu, int V) {
    int l   = threadIdx.x & 63;
    int wid = threadIdx.x >> 6;
    int row0 = blockIdx.x * 256 + wid * 64;      // wave owns rows [row0, row0+64)
    if (row0 >= V * 8) return;
    int lr = l & 15, lg = l >> 4;

    f32x4 acc[4][4];                             // [row tile][col tile]
    #pragma unroll
    for (int ct = 0; ct < 4; ++ct) {
        float b = bias ? bias[ct * 16 + lr] : 0.f;
        #pragma unroll
        for (int rt = 0; rt < 4; ++rt) acc[rt][ct] = (f32x4){b, b, b, b};
    }

    const __half* Ts[4] = {T0, T1, T2, T3};
    #pragma unroll
    for (int s = 0; s < 8; ++s) {
        const __half* tb = Ts[s >> 1];
        size_t ao = (size_t)(row0 + lr) * 64 + (s & 1) * 32 + lg * 8;
        half8v a0 = *(const half8v*)(tb + ao);
        half8v a1 = *(const half8v*)(tb + ao + 16 * 64);
        half8v a2 = *(const half8v*)(tb + ao + 32 * 64);
        half8v a3 = *(const half8v*)(tb + ao + 48 * 64);
        #pragma unroll
        for (int ct = 0; ct < 4; ++ct) {
            half8v bh = *(const half8v*)(Bh + (size_t)(ct * 16 + lr) * 256 + s * 32 + lg * 8);
            half8v bl = *(const half8v*)(Bl + (size_t)(ct * 16 + lr) * 256 + s * 32 + lg * 8);
            acc[0][ct] = __builtin_amdgcn_mfma_f32_16x16x32_f16(a0, bh, acc[0][ct], 0, 0, 0);
            acc[0][ct] = __builtin_amdgcn_mfma_f32_16x16x32_f16(a0, bl, acc[0][ct], 0, 0, 0);
            acc[1][ct] = __builtin_amdgcn_mfma_f32_16x16x32_f16(a1, bh, acc[1][ct], 0, 0, 0);
            acc[1][ct] = __builtin_amdgcn_mfma_f32_16x16x32_f16(a1, bl, acc[1][ct], 0, 0, 0);
            acc[2][ct] = __builtin_amdgcn_mfma_f32_16x16x32_f16(a2, bh, acc[2][ct], 0, 0, 0);
            acc[2][ct] = __builtin_amdgcn_mfma_f32_16x16x32_f16(a2, bl, acc[2][ct], 0, 0, 0);
            acc[3][ct] = __builtin_amdgcn_mfma_f32_16x16x32_f16(a3, bh, acc[3][ct], 0, 0, 0);
            acc[3][ct] = __builtin_amdgcn_mfma_f32_16x16x32_f16(a3, bl, acc[3][ct], 0, 0, 0);
        }
    }
    if (sc) {                                   // 32-ch shortcut, single K-slice
        size_t so = (size_t)(row0 + lr) * 32 + lg * 8;
        half8v c0 = *(const half8v*)(sc + so);
        half8v c1 = *(const half8v*)(sc + so + 16 * 32);
        half8v c2 = *(const half8v*)(sc + so + 32 * 32);
        half8v c3 = *(const half8v*)(sc + so + 48 * 32);
        #pragma unroll
        for (int ct = 0; ct < 4; ++ct) {
            half8v bh = *(const half8v*)(Bsh + (size_t)(ct * 16 + lr) * 32 + lg * 8);
            half8v bl = *(const half8v*)(Bsl + (size_t)(ct * 16 + lr) * 32 + lg * 8);
            acc[0][ct] = __builtin_amdgcn_mfma_f32_16x16x32_f16(c0, bh, acc[0][ct], 0, 0, 0);
            acc[0][ct] = __builtin_amdgcn_mfma_f32_16x16x32_f16(c0, bl, acc[0][ct], 0, 0, 0);
            acc[1][ct] = __builtin_amdgcn_mfma_f32_16x16x32_f16(c1, bh, acc[1][ct], 0, 0, 0);
            acc[1][ct] = __builtin_amdgcn_mfma_f32_16x16x32_f16(c1, bl, acc[1][ct], 0, 0, 0);
            acc[2][ct] = __builtin_amdgcn_mfma_f32_16x16x32_f16(c2, bh, acc[2][ct], 0, 0, 0);
            acc[2][ct] = __builtin_amdgcn_mfma_f32_16x16x32_f16(c2, bl, acc[2][ct], 0, 0, 0);
            acc[3][ct] = __builtin_amdgcn_mfma_f32_16x16x32_f16(c3, bh, acc[3][ct], 0, 0, 0);
            acc[3][ct] = __builtin_amdgcn_mfma_f32_16x16x32_f16(c3, bl, acc[3][ct], 0, 0, 0);
        }
    }

    #pragma unroll
    for (int rt = 0; rt < 4; ++rt) {
        #pragma unroll
        for (int ct = 0; ct < 4; ++ct) {
            #pragma unroll
            for (int j = 0; j < 4; ++j) {
                int r = row0 + rt * 16 + lg * 4 + j;
                int c = ct * 16 + lr;
                float v = acc[rt][ct][j];
                if (res) v += __half2float(res[(size_t)r * 64 + c]);
                if (relu) v = fmaxf(v, 0.f);
                out[(size_t)r * 64 + c] = __float2half_rn(v);
            }
        }
    }
}

// ===========================================================================
// combine32 via MFMA (round-17): same v4 template for CIN=32 (K=128, 4
// slices, one per T — no cross-T fragments). 64 rows/wave, COUT/16 col
// tiles. fp16 two-term W split; MFMA order s asc, h then l -> deterministic.
// Aliasing: W1a call has out==T1 (reads precede writes per wave, ranges
// disjoint); W1b has res==out (per-element read-then-write in-thread).
// ===========================================================================
template <int COUT>
__global__ __launch_bounds__(256) void combine32_mfma_kernel(
    const __half* T0, const __half* T1, const __half* T2, const __half* T3,
    const __half* __restrict__ Bh, const __half* __restrict__ Bl,
    const float* __restrict__ bias, const __half* res,
    __half* out, int relu, int V) {
    constexpr int NCT = COUT / 16;
    int l   = threadIdx.x & 63;
    int wid = threadIdx.x >> 6;
    int row0 = blockIdx.x * 256 + wid * 64;
    if (row0 >= V * 8) return;
    int lr = l & 15, lg = l >> 4;

    f32x4 acc[4][NCT];
    #pragma unroll
    for (int ct = 0; ct < NCT; ++ct) {
        float b = bias ? bias[ct * 16 + lr] : 0.f;
        #pragma unroll
        for (int rt = 0; rt < 4; ++rt) acc[rt][ct] = (f32x4){b, b, b, b};
    }

    const __half* Ts[4] = {T0, T1, T2, T3};
    #pragma unroll
    for (int s = 0; s < 4; ++s) {
        const __half* tb = Ts[s];
        size_t ao = (size_t)(row0 + lr) * 32 + lg * 8;
        half8v a0 = *(const half8v*)(tb + ao);
        half8v a1 = *(const half8v*)(tb + ao + 16 * 32);
        half8v a2 = *(const half8v*)(tb + ao + 32 * 32);
        half8v a3 = *(const half8v*)(tb + ao + 48 * 32);
        #pragma unroll
        for (int ct = 0; ct < NCT; ++ct) {
            half8v bh = *(const half8v*)(Bh + (size_t)(ct * 16 + lr) * 128 + s * 32 + lg * 8);
            half8v bl = *(const half8v*)(Bl + (size_t)(ct * 16 + lr) * 128 + s * 32 + lg * 8);
            acc[0][ct] = __builtin_amdgcn_mfma_f32_16x16x32_f16(a0, bh, acc[0][ct], 0, 0, 0);
            acc[0][ct] = __builtin_amdgcn_mfma_f32_16x16x32_f16(a0, bl, acc[0][ct], 0, 0, 0);
            acc[1][ct] = __builtin_amdgcn_mfma_f32_16x16x32_f16(a1, bh, acc[1][ct], 0, 0, 0);
            acc[1][ct] = __builtin_amdgcn_mfma_f32_16x16x32_f16(a1, bl, acc[1][ct], 0, 0, 0);
            acc[2][ct] = __builtin_amdgcn_mfma_f32_16x16x32_f16(a2, bh, acc[2][ct], 0, 0, 0);
            acc[2][ct] = __builtin_amdgcn_mfma_f32_16x16x32_f16(a2, bl, acc[2][ct], 0, 0, 0);
            acc[3][ct] = __builtin_amdgcn_mfma_f32_16x16x32_f16(a3, bh, acc[3][ct], 0, 0, 0);
            acc[3][ct] = __builtin_amdgcn_mfma_f32_16x16x32_f16(a3, bl, acc[3][ct], 0, 0, 0);
        }
    }

    #pragma unroll
    for (int rt = 0; rt < 4; ++rt) {
        #pragma unroll
        for (int ct = 0; ct < NCT; ++ct) {
            #pragma unroll
            for (int j = 0; j < 4; ++j) {
                int r = row0 + rt * 16 + lg * 4 + j;
                int c = ct * 16 + lr;
                float v = acc[rt][ct][j];
                if (res) v += __half2float(res[(size_t)r * COUT + c]);
                if (relu) v = fmaxf(v, 0.f);
                out[(size_t)r * COUT + c] = __float2half_rn(v);
            }
        }
    }
}

// ===========================================================================
// head combine <64,10> via MFMA (proven r16): 32 rows/wave, one 16-col tile
// (W zero-padded 10->16). Padded cols never written (lr<10 guard).
// ===========================================================================
__global__ __launch_bounds__(256) void combine_head_mfma_kernel(
    const __half* T0, const __half* T1, const __half* T2, const __half* T3,
    const __half* __restrict__ Bh, const __half* __restrict__ Bl,
    const float* __restrict__ bias, __half* out, int V) {
    int l   = threadIdx.x & 63;
    int wid = threadIdx.x >> 6;
    int row0 = blockIdx.x * 128 + wid * 32;
    if (row0 >= V * 8) return;
    int lr = l & 15, lg = l >> 4;

    float b = (lr < 10 && bias) ? bias[lr] : 0.f;
    f32x4 acc0 = (f32x4){b, b, b, b};
    f32x4 acc1 = (f32x4){b, b, b, b};

    const __half* Ts[4] = {T0, T1, T2, T3};
    #pragma unroll
    for (int s = 0; s < 8; ++s) {
        const __half* tb = Ts[s >> 1];
        size_t ao = (size_t)(row0 + lr) * 64 + (s & 1) * 32 + lg * 8;
        half8v a0 = *(const half8v*)(tb + ao);
        half8v a1 = *(const half8v*)(tb + ao + 16 * 64);
        half8v bh = *(const half8v*)(Bh + (size_t)lr * 256 + s * 32 + lg * 8);
        half8v bl = *(const half8v*)(Bl + (size_t)lr * 256 + s * 32 + lg * 8);
        acc0 = __builtin_amdgcn_mfma_f32_16x16x32_f16(a0, bh, acc0, 0, 0, 0);
        acc0 = __builtin_amdgcn_mfma_f32_16x16x32_f16(a0, bl, acc0, 0, 0, 0);
        acc1 = __builtin_amdgcn_mfma_f32_16x16x32_f16(a1, bh, acc1, 0, 0, 0);
        acc1 = __builtin_amdgcn_mfma_f32_16x16x32_f16(a1, bl, acc1, 0, 0, 0);
    }

    if (lr < 10) {
        #pragma unroll
        for (int rt = 0; rt < 2; ++rt) {
            f32x4 acc = rt ? acc1 : acc0;
            #pragma unroll
            for (int j = 0; j < 4; ++j) {
                int r = row0 + rt * 16 + lg * 4 + j;
                float v = fmaxf(acc[j], 0.f);               // head relu
                out[(size_t)r * 10 + lr] = __float2half_rn(v);
            }
        }
    }
}

// ===========================================================================
// combine v11 (scalar path, kept only for 16x32 conv_in)
// ===========================================================================
template <int CIN, int COUT>
__global__ __launch_bounds__(256) void combine_kernel(
    const __half* T0, const __half* T1, const __half* T2, const __half* T3,
    const float* __restrict__ W, const float* __restrict__ bias,
    const __half* res, const __half* sc, const float* __restrict__ Wsc,
    __half* out, int relu, int V) {
    constexpr int SL    = CIN / 8;               // float4 slots per row
    constexpr int BURST = (SL < 4) ? SL : 4;     // 4 float4 = one 64B sector
    constexpr int NB    = SL / BURST;
    constexpr int SLS   = 32 / 8;                // shortcut always 32ch
    union U4 { float4 raw; __half2 h[4]; };
    union UW { float4 raw; v2f p[2]; };

    int g = blockIdx.x * 256 + threadIdx.x;
    if (g >= V * 8) return;

    v2f acc[COUT / 2];
    #pragma unroll
    for (int c = 0; c < COUT / 2; ++c) {
        if (bias) { acc[c].x = bias[2 * c]; acc[c].y = bias[2 * c + 1]; }
        else      { acc[c].x = 0.f;         acc[c].y = 0.f; }
    }

    auto rank1 = [&](float2 a, const float* w0f, const float* w1f) {
        v2f ax = {a.x, a.x}, ay = {a.y, a.y};
        if constexpr (COUT % 4 == 0) {
            const float4* w0 = (const float4*)w0f;
            const float4* w1 = (const float4*)w1f;
            #pragma unroll
            for (int cw = 0; cw < COUT / 4; ++cw) {
                UW A; A.raw = w0[cw];
                UW B; B.raw = w1[cw];
                acc[2 * cw]     = vfma2(ax, A.p[0], acc[2 * cw]);
                acc[2 * cw]     = vfma2(ay, B.p[0], acc[2 * cw]);
                acc[2 * cw + 1] = vfma2(ax, A.p[1], acc[2 * cw + 1]);
                acc[2 * cw + 1] = vfma2(ay, B.p[1], acc[2 * cw + 1]);
            }
        } else {
            const v2f* w0 = (const v2f*)w0f;
            const v2f* w1 = (const v2f*)w1f;
            #pragma unroll
            for (int c = 0; c < COUT / 2; ++c) {
                acc[c] = vfma2(ax, w0[c], acc[c]);
                acc[c] = vfma2(ay, w1[c], acc[c]);
            }
        }
    };

    const __half* Ts[4] = {T0, T1, T2, T3};
    #pragma unroll 1
    for (int k = 0; k < 4; ++k) {
        const float4* rp = (const float4*)(Ts[k] + (size_t)g * CIN);
        const float* Wk = W + (size_t)k * CIN * COUT;
        #pragma unroll 1
        for (int b2 = 0; b2 < NB; ++b2) {
            U4 x[BURST];
            #pragma unroll
            for (int j = 0; j < BURST; ++j) x[j].raw = rp[b2 * BURST + j];
            #pragma unroll
            for (int j = 0; j < BURST; ++j) {
                #pragma unroll
                for (int s = 0; s < 4; ++s) {
                    int q = (b2 * BURST + j) * 4 + s;
                    float2 a = __half22float2(x[j].h[s]);
                    rank1(a, Wk + (size_t)(2 * q) * COUT,
                             Wk + (size_t)(2 * q + 1) * COUT);
                }
            }
        }
    }
    if (sc) {
        const float4* sp = (const float4*)(sc + (size_t)g * 32);
        U4 x[SLS];
        #pragma unroll
        for (int j = 0; j < SLS; ++j) x[j].raw = sp[j];
        #pragma unroll
        for (int j = 0; j < SLS; ++j) {
            #pragma unroll
            for (int s = 0; s < 4; ++s) {
                int q = j * 4 + s;
                float2 a = __half22float2(x[j].h[s]);
                rank1(a, Wsc + (size_t)(2 * q) * COUT,
                         Wsc + (size_t)(2 * q + 1) * COUT);
            }
        }
    }

    size_t ob = (size_t)g * COUT;
    if constexpr (COUT % 8 == 0) {
        if (res) {
            const float4* rr = (const float4*)(res + ob);
            #pragma unroll
            for (int q = 0; q < COUT / 8; ++q) {
                U4 rv; rv.raw = rr[q];
                #pragma unroll
                for (int s = 0; s < 4; ++s) {
                    float2 f = __half22float2(rv.h[s]);
                    acc[q * 4 + s].x += f.x; acc[q * 4 + s].y += f.y;
                }
            }
        }
        if (relu) {
            #pragma unroll
            for (int c = 0; c < COUT / 2; ++c) {
                acc[c].x = fmaxf(acc[c].x, 0.f);
                acc[c].y = fmaxf(acc[c].y, 0.f);
            }
        }
        float4* ro = (float4*)(out + ob);
        #pragma unroll
        for (int q = 0; q < COUT / 8; ++q) {
            U4 o;
            #pragma unroll
            for (int s = 0; s < 4; ++s)
                o.h[s] = __floats2half2_rn(acc[q * 4 + s].x, acc[q * 4 + s].y);
            ro[q] = o.raw;
        }
    } else {
        if (res) {
            const __half2* rr = (const __half2*)(res + ob);
            #pragma unroll
            for (int c = 0; c < COUT / 2; ++c) {
                float2 f = __half22float2(rr[c]);
                acc[c].x += f.x; acc[c].y += f.y;
            }
        }
        if (relu) {
            #pragma unroll
            for (int c = 0; c < COUT / 2; ++c) {
                acc[c].x = fmaxf(acc[c].x, 0.f);
                acc[c].y = fmaxf(acc[c].y, 0.f);
            }
        }
        __half2* ro = (__half2*)(out + ob);
        #pragma unroll
        for (int c = 0; c < COUT / 2; ++c)
            ro[c] = __floats2half2_rn(acc[c].x, acc[c].y);
    }
}

// ===========================================================================
// BatchNorm: two-stage deterministic stats (no float atomics), SB=512.
// ===========================================================================
__global__ void bn_stats_part_kernel(const __half2* __restrict__ x2, int C, int relu_in,
                                     float* __restrict__ part, size_t N2) {
    __shared__ float sx[256], qx[256], sy[256], qy[256];
    int t = threadIdx.x;
    size_t i0 = (size_t)blockIdx.x * 256 + t;
    size_t step = (size_t)gridDim.x * 256;
    float ax = 0.f, aqx = 0.f, ay = 0.f, aqy = 0.f;
    for (size_t i = i0; i < N2; i += step) {
        float2 f = __half22float2(x2[i]);
        if (relu_in) { f.x = fmaxf(f.x, 0.f); f.y = fmaxf(f.y, 0.f); }
        ax += f.x; aqx += f.x * f.x;
        ay += f.y; aqy += f.y * f.y;
    }
    sx[t] = ax; qx[t] = aqx; sy[t] = ay; qy[t] = aqy;
    __syncthreads();
    int half = C >> 1;
    for (int st = 128; st >= half; st >>= 1) {
        if (t < st) {
            sx[t] += sx[t + st]; qx[t] += qx[t + st];
            sy[t] += sy[t + st]; qy[t] += qy[t + st];
        }
        __syncthreads();
    }
    if (t < half) {
        part[blockIdx.x * 128 + 2 * t]         = sx[t];
        part[blockIdx.x * 128 + 2 * t + 1]     = sy[t];
        part[blockIdx.x * 128 + C + 2 * t]     = qx[t];
        part[blockIdx.x * 128 + C + 2 * t + 1] = qy[t];
    }
}

__global__ void bn_reduce_kernel(const float* __restrict__ part, int nblk,
                                 const float* __restrict__ g, const float* __restrict__ be,
                                 float* __restrict__ ss, int C, float invN) {
    int c = threadIdx.x;
    if (c < C) {
        float s = 0.f, q = 0.f;
        for (int b = 0; b < nblk; ++b) {        // fixed order -> deterministic
            s += part[b * 128 + c];
            q += part[b * 128 + C + c];
        }
        float m = s * invN;
        float var = q * invN - m * m;
        float sc = g[c] * rsqrtf(var + 1e-5f);
        ss[c] = sc;
        ss[C + c] = be[c] - m * sc;
    }
}

// in-place: x = f(x)*a + b, f = relu if relu_in. float4-vectorized.
__global__ void affine_h_kernel(__half* x, const float* __restrict__ ss, int C,
                                int relu_in, size_t N2) {
    union U4 { float4 raw; __half2 h[4]; };
    size_t NG = N2 >> 2;
    size_t stride = (size_t)gridDim.x * blockDim.x;
    size_t i0 = (size_t)blockIdx.x * blockDim.x + threadIdx.x;
    float4* x4 = (float4*)x;
    int c0 = (int)((8 * i0) & (size_t)(C - 1));
    float sc[8], of[8];
    #pragma unroll
    for (int j = 0; j < 8; ++j) { sc[j] = ss[c0 + j]; of[j] = ss[C + c0 + j]; }
    for (size_t i = i0; i < NG; i += stride) {
        U4 u; u.raw = x4[i];
        #pragma unroll
        for (int j = 0; j < 4; ++j) {
            float2 f = __half22float2(u.h[j]);
            if (relu_in) { f.x = fmaxf(f.x, 0.f); f.y = fmaxf(f.y, 0.f); }
            f.x = f.x * sc[2 * j] + of[2 * j];
            f.y = f.y * sc[2 * j + 1] + of[2 * j + 1];
            u.h[j] = __floats2half2_rn(f.x, f.y);
        }
        x4[i] = u.raw;
    }
}

// ===========================================================================
// head: partial max + int-atomicMax, then log_softmax
// ===========================================================================
__global__ void maxpool_h_kernel(const __half* __restrict__ x, float* pooled, int V, int NS) {
    __shared__ float red[256];
    int o = blockIdx.x % 80;
    int slice = blockIdx.x / 80;
    int v0 = (int)((long long)V * slice / NS);
    int v1 = (int)((long long)V * (slice + 1) / NS);
    float m = 0.f;
    for (int v = v0 + threadIdx.x; v < v1; v += 256)
        m = fmaxf(m, __half2float(x[(size_t)v * 80 + o]));
    red[threadIdx.x] = m;
    __syncthreads();
    for (int st = 128; st > 0; st >>= 1) {
        if (threadIdx.x < st) red[threadIdx.x] = fmaxf(red[threadIdx.x], red[threadIdx.x + st]);
        __syncthreads();
    }
    if (threadIdx.x == 0) atomicMax((int*)&pooled[o], __float_as_int(red[0]));
}

__global__ void lsm_kernel(const float* __restrict__ pooled, float* __restrict__ out) {
    int b = threadIdx.x;
    if (b < 8) {
        float m = -1e30f;
        for (int c = 0; c < 10; ++c) m = fmaxf(m, pooled[b * 10 + c]);
        float s = 0.f;
        for (int c = 0; c < 10; ++c) s += expf(pooled[b * 10 + c] - m);
        float l = logf(s);
        for (int c = 0; c < 10; ++c)
            out[b * 10 + c] = pooled[b * 10 + c] - m - l;
    }
}

__global__ void encode_kernel(float* out, float val) {
    int i = threadIdx.x;
    if (i < 80) out[i] = val;
}

// ===========================================================================
// entry
// ===========================================================================
extern "C" void kernel_launch(void* const* d_in, const int* in_sizes, int n_in,
                              void* d_out, int out_size, void* d_ws, size_t ws_size,
                              hipStream_t stream) {
    (void)in_sizes; (void)n_in; (void)out_size;
    const int V = 50000, E = 800000;
    const int NCH = (V + 255) / 256;
    const int SB = 512;                       // bn stage-1 blocks
    const int NS = 8;                         // maxpool node slices

    auto al = [](size_t x) { return (x + 255) & ~(size_t)255; };
    const size_t FB = al((size_t)V * 512 * sizeof(__half));     // 51.2 MB
    const size_t WPB = al((size_t)256 * 64 * 2) * 2 + al((size_t)32 * 64 * 2) * 2
                     + al((size_t)256 * 16 * 2) * 2;
    const size_t need = 5 * FB + al((V + 1) * 4) + al(V * 4) + al(E * 4) + al(E * 4)
                      + al((size_t)SB * 128 * 4) + al(8 * 128 * 4) + al(80 * 4) + al(NCH * 4)
                      + WPB;
    if (ws_size < need) {
        encode_kernel<<<1, 128, 0, stream>>>((float*)d_out, (float)(ws_size >> 20));
        return;
    }

    const float* x_in = (const float*)d_in[0];
    const int* rows   = (const int*)d_in[1];
    const int* colsi  = (const int*)d_in[2];
    const float* lvals = (const float*)d_in[3];
    const float* W_in = (const float*)d_in[4];
    const float* b_in = (const float*)d_in[5];
    const float* g1a = (const float*)d_in[6],  *be1a = (const float*)d_in[7];
    const float* W1a = (const float*)d_in[8],  *b1a  = (const float*)d_in[9];
    const float* g1b = (const float*)d_in[10], *be1b = (const float*)d_in[11];
    const float* W1b = (const float*)d_in[12], *b1b  = (const float*)d_in[13];
    const float* g2a = (const float*)d_in[14], *be2a = (const float*)d_in[15];
    const float* W2a = (const float*)d_in[16], *b2a  = (const float*)d_in[17];
    const float* g2b = (const float*)d_in[18], *be2b = (const float*)d_in[19];
    const float* W2b = (const float*)d_in[20], *b2b  = (const float*)d_in[21];
    const float* W2s = (const float*)d_in[22];
    const float* g3a = (const float*)d_in[23], *be3a = (const float*)d_in[24];
    const float* W3a = (const float*)d_in[25], *b3a  = (const float*)d_in[26];
    const float* g3b = (const float*)d_in[27], *be3b = (const float*)d_in[28];
    const float* W3b = (const float*)d_in[29], *b3b  = (const float*)d_in[30];
    const float* g_o = (const float*)d_in[31], *be_o = (const float*)d_in[32];
    const float* W_o = (const float*)d_in[33], *b_o  = (const float*)d_in[34];

    char* wp = (char*)d_ws;
    auto take = [&](size_t bytes) -> void* { void* p = (void*)wp; wp += al(bytes); return p; };
    __half* P0 = (__half*)take(FB);
    __half* P1 = (__half*)take(FB);
    __half* P2 = (__half*)take(FB);
    __half* P3 = (__half*)take(FB);
    __half* P4 = (__half*)take(FB);
    int* row_ptr  = (int*)take((V + 1) * sizeof(int));
    int* cursor   = (int*)take(V * sizeof(int));
    int* cols_s   = (int*)take(E * sizeof(int));
    float* vals_s = (float*)take(E * sizeof(float));
    float* part   = (float*)take((size_t)SB * 128 * sizeof(float));
    float* aff    = (float*)take(8 * 128 * sizeof(float));
    float* pooled = (float*)take(80 * sizeof(float));
    int* chunks   = (int*)take(NCH * sizeof(int));
    __half* wbh   = (__half*)take((size_t)256 * 64 * 2);
    __half* wbl   = (__half*)take((size_t)256 * 64 * 2);
    __half* wsh   = (__half*)take((size_t)32 * 64 * 2);
    __half* wsl   = (__half*)take((size_t)32 * 64 * 2);
    __half* whh   = (__half*)take((size_t)256 * 16 * 2);
    __half* whl   = (__half*)take((size_t)256 * 16 * 2);

    hipMemsetAsync(cursor, 0, V * sizeof(int), stream);
    hipMemsetAsync(pooled, 0, 80 * sizeof(float), stream);

    // ---- CSR build (+canonical row order) + input transpose ----
    hist_kernel<<<(E + 255) / 256, 256, 0, stream>>>(rows, cursor, E);
    chunk_sum_kernel<<<NCH, 256, 0, stream>>>(cursor, chunks, V);
    scan_chunks_kernel<<<1, 256, 0, stream>>>(chunks, NCH);
    scan_final_kernel<<<NCH, 256, 0, stream>>>(cursor, chunks, row_ptr, V);
    init_cursor_kernel<<<(V + 255) / 256, 256, 0, stream>>>(row_ptr, cursor, V);
    scatter_kernel<<<(E + 255) / 256, 256, 0, stream>>>(rows, colsi, lvals, cursor, cols_s, vals_s, E);
    sort_rows_kernel<<<(V + 255) / 256, 256, 0, stream>>>(row_ptr, cols_s, vals_s, V);
    transpose_in_kernel<<<4096, 256, 0, stream>>>(x_in, P0, V);

    // ---- helpers ----
    const int SG = (V + 3) / 4;
    auto spmm = [&](const __half* src, __half* dst, const __half* prev, int C) {
        if (C == 16)
            spmm2_kernel<1><<<SG, 256, 0, stream>>>(row_ptr, cols_s, vals_s,
                (const __half2*)src, (__half2*)dst, (const __half2*)prev, V);
        else if (C == 32)
            spmm2_kernel<2><<<SG, 256, 0, stream>>>(row_ptr, cols_s, vals_s,
                (const __half2*)src, (__half2*)dst, (const __half2*)prev, V);
        else
            spmm2_kernel<4><<<SG, 256, 0, stream>>>(row_ptr, cols_s, vals_s,
                (const __half2*)src, (__half2*)dst, (const __half2*)prev, V);
    };
    auto cheb3 = [&](const __half* a, __half* b, __half* c, __half* d, int C) {
        spmm(a, b, nullptr, C);
        spmm(b, c, a, C);
        spmm(c, d, b, C);
    };
    const int MG = (V * 8 + 255) / 256;
    auto comb = [&](const __half* T0, const __half* T1, const __half* T2, const __half* T3,
                    int Cin, int Cout, const float* W, const float* bias,
                    const __half* res, const __half* sc, const float* Wsc,
                    __half* out, int relu) {
        if (Cin == 64 && Cout == 64) {
            wprep_kernel<<<(256 * 64 + 255) / 256, 256, 0, stream>>>(W, wbh, wbl, 256, 64);
            if (sc) wprep_kernel<<<(32 * 64 + 255) / 256, 256, 0, stream>>>(Wsc, wsh, wsl, 32, 64);
            combine64_mfma_kernel<<<(V * 8 + 255) / 256, 256, 0, stream>>>(
                T0, T1, T2, T3, wbh, wbl, bias, res, sc, wsh, wsl, out, relu, V);
        } else if (Cin == 64 && Cout == 10) {
            wprep_head_kernel<<<(256 * 16 + 255) / 256, 256, 0, stream>>>(W, whh, whl);
            combine_head_mfma_kernel<<<(V * 8 + 127) / 128, 256, 0, stream>>>(
                T0, T1, T2, T3, whh, whl, bias, out, V);
        } else if (Cin == 32 && Cout == 32) {
            wprep_kernel<<<(128 * 32 + 255) / 256, 256, 0, stream>>>(W, wbh, wbl, 128, 32);
            combine32_mfma_kernel<32><<<(V * 8 + 255) / 256, 256, 0, stream>>>(
                T0, T1, T2, T3, wbh, wbl, bias, res, out, relu, V);
        } else if (Cin == 32 && Cout == 64) {
            wprep_kernel<<<(128 * 64 + 255) / 256, 256, 0, stream>>>(W, wbh, wbl, 128, 64);
            combine32_mfma_kernel<64><<<(V * 8 + 255) / 256, 256, 0, stream>>>(
                T0, T1, T2, T3, wbh, wbl, bias, res, out, relu, V);
        } else
            combine_kernel<16, 32><<<MG, 256, 0, stream>>>(T0, T1, T2, T3, W, bias, res, sc, Wsc, out, relu, V);
    };
    auto stats = [&](const __half* xb, int C, int relu, int slot, const float* g, const float* be) {
        bn_stats_part_kernel<<<SB, 256, 0, stream>>>((const __half2*)xb, C, relu, part,
                                                     (size_t)V * 4 * C);
        bn_reduce_kernel<<<1, 64, 0, stream>>>(part, SB, g, be, aff + slot * 128, C,
                                               1.f / ((float)V * 8.f));
    };
    auto affine = [&](__half* xb, int C, int relu, int slot) {
        affine_h_kernel<<<2048, 256, 0, stream>>>(xb, aff + slot * 128, C, relu,
                                                  (size_t)V * 4 * C);
    };
    const __half* NH = nullptr;
    const float*  NF = nullptr;

    // ---- conv_in: x=P0 (16ch) -> relu(cheb+b) -> P4 (32ch) ----
    cheb3(P0, P1, P2, P3, 16);
    comb(P0, P1, P2, P3, 16, 32, W_in, b_in, NH, NH, NF, P4, 1);

    // ---- block 1 (X=P4, 32ch, identity shortcut) ----
    stats(P4, 32, 0, 0, g1a, be1a);
    affine(P4, 32, 0, 0);                   // P4 = xn
    cheb3(P4, P0, P1, P2, 32);
    comb(P4, P0, P1, P2, 32, 32, W1a, b1a, NH, NH, NF, P0, 0);   // out_a = P0 (MFMA)
    stats(P0, 32, 1, 1, g1b, be1b);
    affine(P0, 32, 1, 1);                   // P0 = y
    cheb3(P0, P1, P2, P3, 32);
    comb(P0, P1, P2, P3, 32, 32, W1b, b1b, P4, NH, NF, P4, 1);   // P4 = block1 out (MFMA)

    // ---- block 2 (X=P4, 32ch -> 64ch, W2s shortcut) ----
    stats(P4, 32, 0, 2, g2a, be2a);
    affine(P4, 32, 0, 2);                   // P4 = xn (32ch)
    cheb3(P4, P0, P1, P2, 32);
    comb(P4, P0, P1, P2, 32, 64, W2a, b2a, NH, NH, NF, P3, 0);   // out_a = P3 (MFMA)
    stats(P3, 64, 1, 3, g2b, be2b);
    affine(P3, 64, 1, 3);                   // P3 = y
    cheb3(P3, P0, P1, P2, 64);
    comb(P3, P0, P1, P2, 64, 64, W2b, b2b, NH, P4, W2s, P0, 1);  // P0 = block2 out (MFMA)

    // ---- block 3 (X=P0, 64ch, identity shortcut) ----
    stats(P0, 64, 0, 4, g3a, be3a);
    affine(P0, 64, 0, 4);                   // P0 = xn
    cheb3(P0, P1, P2, P3, 64);
    comb(P0, P1, P2, P3, 64, 64, W3a, b3a, NH, NH, NF, P1, 0);   // out_a = P1 (MFMA)
    stats(P1, 64, 1, 5, g3b, be3b);
    affine(P1, 64, 1, 5);                   // P1 = y
    cheb3(P1, P2, P3, P4, 64);
    comb(P1, P2, P3, P4, 64, 64, W3b, b3b, P0, NH, NF, P1, 1);   // P1 = block3 out (MFMA)

    // ---- head: bn -> relu(cheb 64->10) -> maxpool -> log_softmax ----
    stats(P1, 64, 0, 6, g_o, be_o);
    affine(P1, 64, 0, 6);                   // P1 = bn(x)
    cheb3(P1, P0, P2, P3, 64);
    comb(P1, P0, P2, P3, 64, 10, W_o, b_o, NH, NH, NF, P4, 1);   // P4 logits (MFMA head)
    maxpool_h_kernel<<<80 * NS, 256, 0, stream>>>(P4, pooled, V, NS);
    lsm_kernel<<<1, 64, 0, stream>>>(pooled, (float*)d_out);
}